// Round 11
// baseline (1058.892 us; speedup 1.0000x reference)
//
#include <hip/hip_runtime.h>
#include <hip/hip_fp16.h>
#include <math.h>

#define BB 512
#define NN 64
#define KNB 16
#define NPTS (BB*NN)        // 32768
#define NEDGE (BB*NN*KNB)   // 524288
#define EPSV 1e-5f

typedef __attribute__((ext_vector_type(8))) _Float16 f16x8;
typedef __attribute__((ext_vector_type(4))) _Float16 f16x4;
typedef __attribute__((ext_vector_type(4))) float f32x4;

__device__ __forceinline__ float lrelu(float x){ return fmaxf(x, 0.2f*x); }
__device__ __forceinline__ unsigned encf(float f){
    unsigned u = __float_as_uint(f);
    return (u & 0x80000000u) ? ~u : (u | 0x80000000u);
}
__device__ __forceinline__ float decf(unsigned e){
    unsigned u = (e & 0x80000000u) ? (e ^ 0x80000000u) : ~e;
    return __uint_as_float(u);
}
#define ENC_NEGINF 0x007FFFFFu   // encf(-inf)

__device__ __forceinline__ float dec_ec(unsigned e, float ca, float cb, float gv){
    if (e == ENC_NEGINF) return 0.0f;
    float s = (gv < 0.0f) ? -1.0f : 1.0f;
    return lrelu(ca*(s*decf(e)) + cb);
}

__device__ __forceinline__ void split2h(float v, _Float16& h, _Float16& m){
    h = (_Float16)v;
    float r = v - (float)h;
    m = (_Float16)(r * 2048.0f);
}

// ---------------- input MLP ----------------
__global__ void k_input(const float* __restrict__ x, const float* __restrict__ w,
                        float* __restrict__ h0){
    __shared__ float wls[6*64];
    int t = threadIdx.x;
    for (int i = t; i < 6*64; i += 256) wls[i] = w[i];
    __syncthreads();
    int row = blockIdx.x*256 + t;
    float xv[6];
#pragma unroll
    for (int k = 0; k < 6; k++) xv[k] = x[row*6 + k];
#pragma unroll 8
    for (int c = 0; c < 64; c++){
        float acc = 0.f;
#pragma unroll
        for (int k = 0; k < 6; k++) acc += xv[k]*wls[k*64 + c];
        h0[(size_t)row*64 + c] = acc;
    }
}

// ---- column stats, deterministic partials ----
__global__ void k_colstats_part(const float* __restrict__ h,
                                float* __restrict__ pS, float* __restrict__ pQ){
    int t = threadIdx.x;
    int c = t & 63;
    int g = t >> 6;
    int p = blockIdx.x*4 + g;
    const int rpb = NPTS/256;
    int r0 = p*rpb;
    float s = 0.f, q = 0.f;
    for (int r = r0; r < r0 + rpb; r++){
        float v = h[(size_t)r*64 + c];
        s += v; q += v*v;
    }
    pS[c*256 + p] = s;
    pQ[c*256 + p] = q;
}

// ---- BN finalize from partials (deterministic serial reduce) ----
__global__ void k_bnfin_part(const float* __restrict__ pS, const float* __restrict__ pQ,
                             const float* __restrict__ g, const float* __restrict__ b,
                             float* __restrict__ cA, float* __restrict__ cB,
                             int P, float invM){
    int c = threadIdx.x;
    const float* ps = pS + (size_t)c*P;
    const float* pq = pQ + (size_t)c*P;
    float s = 0.f, q = 0.f;
    for (int p = 0; p < P; p += 4){
        float4 vs = *(const float4*)(ps + p);
        float4 vq = *(const float4*)(pq + p);
        s += vs.x + vs.y + vs.z + vs.w;
        q += vq.x + vq.y + vq.z + vq.w;
    }
    float m = s*invM;
    float v = q*invM - m*m;
    v = v < 0.f ? 0.f : v;
    float a = g[c]*rsqrtf(v + EPSV);
    cA[c] = a;
    cB[c] = b[c] - m*a;
}

// ---- merged weight prep: all three stages in one launch (176 blocks) ----
__global__ void k_wprep_all(const float* __restrict__ w1a, const float* __restrict__ w2a,
                            const float* __restrict__ w3a,
                            _Float16* __restrict__ w1bh, _Float16* __restrict__ w1bm,
                            _Float16* __restrict__ w1dh, _Float16* __restrict__ w1dm,
                            _Float16* __restrict__ w2bh, _Float16* __restrict__ w2bm,
                            _Float16* __restrict__ w2dh, _Float16* __restrict__ w2dm,
                            _Float16* __restrict__ w3bh, _Float16* __restrict__ w3dh){
    int blk = blockIdx.x, t = threadIdx.x;
    if (blk < 16){
        const int CIN = 64, CMID = 64;
        int i = blk*256 + t;
        int k = i / CMID, c = i - k*CMID;
        float wb = w1a[(size_t)(CIN + k)*CMID + c];
        float wd = w1a[(size_t)k*CMID + c] - wb;
        size_t o = (size_t)c*CIN + k;
        _Float16 h, m;
        split2h(wb, h, m); w1bh[o] = h; w1bm[o] = m;
        split2h(wd, h, m); w1dh[o] = h; w1dm[o] = m;
    } else if (blk < 48){
        const int CIN = 64, CMID = 128;
        int i = (blk - 16)*256 + t;
        int k = i / CMID, c = i - k*CMID;
        float wb = w2a[(size_t)(CIN + k)*CMID + c];
        float wd = w2a[(size_t)k*CMID + c] - wb;
        size_t o = (size_t)c*CIN + k;
        _Float16 h, m;
        split2h(wb, h, m); w2bh[o] = h; w2bm[o] = m;
        split2h(wd, h, m); w2dh[o] = h; w2dm[o] = m;
    } else {
        const int CIN = 128, CMID = 256;
        int i = (blk - 48)*256 + t;
        int k = i / CMID, c = i - k*CMID;
        float wb = w3a[(size_t)(CIN + k)*CMID + c];
        float wd = w3a[(size_t)k*CMID + c] - wb;
        size_t o = (size_t)c*CIN + k;
        w3bh[o] = (_Float16)wb;
        w3dh[o] = (_Float16)wd;
    }
}

// ---- k_ec1: fused {decode -> knn -> P/Q GEMM -> edge stats} (stages 1,2) ------
template<int CIN, int CMID, int MODE>
__global__ __launch_bounds__(256)
void k_ec1(const void* __restrict__ xin,
           const float* __restrict__ cA, const float* __restrict__ cB,
           const float* __restrict__ g,
           const _Float16* __restrict__ wbh, const _Float16* __restrict__ wbm,
           const _Float16* __restrict__ wdh, const _Float16* __restrict__ wdm,
           int* __restrict__ idxg,
           float* __restrict__ P, float* __restrict__ Q,
           float* __restrict__ pS, float* __restrict__ pQ){
    const int CP  = CIN + 4;
    const int ASP = CMID + 9;
    constexpr int BA = 64*(CIN+4)*4 + 64*64*4 + 64*4;
    constexpr int BBY = 2*64*(CMID+9)*4;
    constexpr int UB = (BA > BBY) ? BA : BBY;
    __shared__ __align__(16) char ubuf[UB];
    __shared__ int ils[1024];
    float* xls = (float*)ubuf;
    float* dls = (float*)(ubuf + (size_t)64*CP*4);
    float* sq  = (float*)(ubuf + (size_t)64*CP*4 + (size_t)64*64*4);
    float* Pls = (float*)ubuf;
    float* Qls = (float*)(ubuf + (size_t)64*ASP*4);

    int t = threadIdx.x, b = blockIdx.x;
    int lane = t & 63, w = t >> 6;
    int lrow = lane & 15, lk = lane >> 4;

    if (MODE == 0){
        const float* xb = (const float*)xin + (size_t)b*64*CIN;
        for (int i = t; i < 64*CIN; i += 256){
            int n = i / CIN, c = i & (CIN-1);
            xls[n*CP + c] = lrelu(cA[c]*xb[i] + cB[c]);
        }
    } else {
        const unsigned* xb = (const unsigned*)xin + (size_t)b*64*CIN;
        for (int i = t; i < 64*CIN; i += 256){
            int n = i / CIN, c = i & (CIN-1);
            xls[n*CP + c] = dec_ec(xb[i], cA[c], cB[c], g[c]);
        }
    }
    __syncthreads();
    if (t < 64){
        float s = 0.f;
        for (int c = 0; c < CIN; c += 4){
            float4 v = *(const float4*)&xls[t*CP + c];
            s += v.x*v.x + v.y*v.y + v.z*v.z + v.w*v.w;
        }
        sq[t] = s;
    }
    __syncthreads();
    {
        int n0 = (t >> 3)*2;
        int m0 = (t & 7)*8;
        float acc[2][8];
#pragma unroll
        for (int r = 0; r < 2; r++)
#pragma unroll
            for (int i = 0; i < 8; i++) acc[r][i] = 0.f;
        const float* an0 = &xls[n0*CP];
        const float* an1 = &xls[(n0+1)*CP];
        const float* bm  = &xls[m0*CP];
        for (int c = 0; c < CIN; c += 4){
            float4 a0 = *(const float4*)(an0 + c);
            float4 a1 = *(const float4*)(an1 + c);
#pragma unroll
            for (int i = 0; i < 8; i++){
                float4 bv = *(const float4*)(bm + i*CP + c);
                acc[0][i] += a0.x*bv.x + a0.y*bv.y + a0.z*bv.z + a0.w*bv.w;
                acc[1][i] += a1.x*bv.x + a1.y*bv.y + a1.z*bv.z + a1.w*bv.w;
            }
        }
#pragma unroll
        for (int r = 0; r < 2; r++){
            float sn = sq[n0 + r];
#pragma unroll
            for (int i4 = 0; i4 < 8; i4 += 4){
                float4 dv;
                dv.x = sn - 2.0f*acc[r][i4+0] + sq[m0+i4+0];
                dv.y = sn - 2.0f*acc[r][i4+1] + sq[m0+i4+1];
                dv.z = sn - 2.0f*acc[r][i4+2] + sq[m0+i4+2];
                dv.w = sn - 2.0f*acc[r][i4+3] + sq[m0+i4+3];
                *(float4*)&dls[(n0+r)*64 + m0 + i4] = dv;
            }
        }
    }
    __syncthreads();
    for (int pr = 0; pr < 16; pr += 4){
        int n0 = w*16 + pr;
        unsigned long long c0 = (((unsigned long long)encf(dls[(n0+0)*64 + lane])) << 32) | (unsigned)lane;
        unsigned long long c1 = (((unsigned long long)encf(dls[(n0+1)*64 + lane])) << 32) | (unsigned)lane;
        unsigned long long c2 = (((unsigned long long)encf(dls[(n0+2)*64 + lane])) << 32) | (unsigned)lane;
        unsigned long long c3 = (((unsigned long long)encf(dls[(n0+3)*64 + lane])) << 32) | (unsigned)lane;
#pragma unroll
        for (int k = 2; k <= 64; k <<= 1){
#pragma unroll
            for (int j = k >> 1; j > 0; j >>= 1){
                bool keepmin = ((lane & j) == 0) == ((lane & k) == 0);
                unsigned long long o0 = __shfl_xor(c0, j, 64);
                unsigned long long o1 = __shfl_xor(c1, j, 64);
                unsigned long long o2 = __shfl_xor(c2, j, 64);
                unsigned long long o3 = __shfl_xor(c3, j, 64);
                c0 = keepmin ? (c0 < o0 ? c0 : o0) : (c0 < o0 ? o0 : c0);
                c1 = keepmin ? (c1 < o1 ? c1 : o1) : (c1 < o1 ? o1 : c1);
                c2 = keepmin ? (c2 < o2 ? c2 : o2) : (c2 < o2 ? o2 : c2);
                c3 = keepmin ? (c3 < o3 ? c3 : o3) : (c3 < o3 ? o3 : c3);
            }
        }
        if (lane >= 1 && lane <= KNB){
            int lb = n0*16 + lane - 1;
            int base = b*1024 + lb;
            int v0 = (int)(c0 & 0xffffffffu);
            int v1 = (int)(c1 & 0xffffffffu);
            int v2 = (int)(c2 & 0xffffffffu);
            int v3 = (int)(c3 & 0xffffffffu);
            idxg[base]      = v0; ils[lb]      = v0;
            idxg[base + 16] = v1; ils[lb + 16] = v1;
            idxg[base + 32] = v2; ils[lb + 32] = v2;
            idxg[base + 48] = v3; ils[lb + 48] = v3;
        }
    }
    const int KT = CIN/32;
    f16x8 ah[KT], am[KT];
    {
        const float* xr = &xls[(w*16 + lrow)*CP];
#pragma unroll
        for (int kt = 0; kt < KT; kt++){
            union { f16x8 v; _Float16 u[8]; } H, M;
#pragma unroll
            for (int j = 0; j < 8; j++)
                split2h(xr[kt*32 + lk*8 + j], H.u[j], M.u[j]);
            ah[kt] = H.v; am[kt] = M.v;
        }
    }
    __syncthreads();   // all xls/dls reads done before Pls/Qls overwrite
#pragma unroll
    for (int ct = 0; ct < CMID/16; ct++){
        int col = ct*16 + lrow;
        f32x4 aPM = {0,0,0,0}, aPC = {0,0,0,0};
        f32x4 aQM = {0,0,0,0}, aQC = {0,0,0,0};
#pragma unroll
        for (int kt = 0; kt < KT; kt++){
            size_t bo = (size_t)col*CIN + kt*32 + lk*8;
            f16x8 bbh = *(const f16x8*)(wbh + bo);
            f16x8 bbm = *(const f16x8*)(wbm + bo);
            f16x8 bdh = *(const f16x8*)(wdh + bo);
            f16x8 bdm = *(const f16x8*)(wdm + bo);
            aPM = __builtin_amdgcn_mfma_f32_16x16x32_f16(ah[kt], bbh, aPM, 0, 0, 0);
            aPC = __builtin_amdgcn_mfma_f32_16x16x32_f16(ah[kt], bbm, aPC, 0, 0, 0);
            aPC = __builtin_amdgcn_mfma_f32_16x16x32_f16(am[kt], bbh, aPC, 0, 0, 0);
            aQM = __builtin_amdgcn_mfma_f32_16x16x32_f16(ah[kt], bdh, aQM, 0, 0, 0);
            aQC = __builtin_amdgcn_mfma_f32_16x16x32_f16(ah[kt], bdm, aQC, 0, 0, 0);
            aQC = __builtin_amdgcn_mfma_f32_16x16x32_f16(am[kt], bdh, aQC, 0, 0, 0);
        }
#pragma unroll
        for (int u = 0; u < 4; u++){
            int row = w*16 + lk*4 + u;
            size_t o = ((size_t)b*64 + row)*CMID + col;
            float pv = aPM[u] + aPC[u]*(1.0f/2048.0f);
            float qv = aQM[u] + aQC[u]*(1.0f/2048.0f);
            P[o] = pv; Q[o] = qv;
            Pls[row*ASP + col] = pv;
            Qls[row*ASP + col] = qv;
        }
    }
    __syncthreads();
    {
        const int NG = 256/CMID;
        const int PT = 512*NG;
        const int NPG = 64/NG;
        int c  = t & (CMID-1);
        int gg = t / CMID;
        float s = 0.f, q = 0.f;
        for (int n = gg*NPG; n < (gg+1)*NPG; n++){
            float p = Pls[n*ASP + c];
#pragma unroll 4
            for (int k = 0; k < 16; k++){
                int j = ils[n*16 + k];
                float v = p + Qls[j*ASP + c];
                s += v; q += v*v;
            }
        }
        int p = b*NG + gg;
        pS[(size_t)c*PT + p] = s;
        pQ[(size_t)c*PT + p] = q;
    }
}

// ---- k_ec1h: fused {decode -> knn -> f16 GEMM -> stats} (stage 3) -------------
template<int CIN, int CMID>
__global__ __launch_bounds__(256)
void k_ec1h(const unsigned* __restrict__ xin,
            const float* __restrict__ cA, const float* __restrict__ cB,
            const float* __restrict__ g,
            const _Float16* __restrict__ wbh, const _Float16* __restrict__ wdh,
            int* __restrict__ idxg,
            _Float16* __restrict__ P, _Float16* __restrict__ Q,
            float* __restrict__ pS, float* __restrict__ pQ){
    const int CP  = CIN + 4;
    const int ASP = CMID + 9;
    constexpr int BA = 64*(CIN+4)*4 + 64*64*4 + 64*4;
    constexpr int BBY = 2*64*(CMID+9)*2;
    constexpr int UB = (BA > BBY) ? BA : BBY;
    __shared__ __align__(16) char ubuf[UB];
    __shared__ int ils[1024];
    float* xls = (float*)ubuf;
    float* dls = (float*)(ubuf + (size_t)64*CP*4);
    float* sq  = (float*)(ubuf + (size_t)64*CP*4 + (size_t)64*64*4);
    _Float16* Pls = (_Float16*)ubuf;
    _Float16* Qls = (_Float16*)(ubuf + (size_t)64*ASP*2);

    int t = threadIdx.x, b = blockIdx.x;
    int lane = t & 63, w = t >> 6;
    int lrow = lane & 15, lk = lane >> 4;

    {
        const unsigned* xb = xin + (size_t)b*64*CIN;
        for (int i = t; i < 64*CIN; i += 256){
            int n = i / CIN, c = i & (CIN-1);
            xls[n*CP + c] = dec_ec(xb[i], cA[c], cB[c], g[c]);
        }
    }
    __syncthreads();
    if (t < 64){
        float s = 0.f;
        for (int c = 0; c < CIN; c += 4){
            float4 v = *(const float4*)&xls[t*CP + c];
            s += v.x*v.x + v.y*v.y + v.z*v.z + v.w*v.w;
        }
        sq[t] = s;
    }
    __syncthreads();
    {
        int n0 = (t >> 3)*2;
        int m0 = (t & 7)*8;
        float acc[2][8];
#pragma unroll
        for (int r = 0; r < 2; r++)
#pragma unroll
            for (int i = 0; i < 8; i++) acc[r][i] = 0.f;
        const float* an0 = &xls[n0*CP];
        const float* an1 = &xls[(n0+1)*CP];
        const float* bm  = &xls[m0*CP];
        for (int c = 0; c < CIN; c += 4){
            float4 a0 = *(const float4*)(an0 + c);
            float4 a1 = *(const float4*)(an1 + c);
#pragma unroll
            for (int i = 0; i < 8; i++){
                float4 bv = *(const float4*)(bm + i*CP + c);
                acc[0][i] += a0.x*bv.x + a0.y*bv.y + a0.z*bv.z + a0.w*bv.w;
                acc[1][i] += a1.x*bv.x + a1.y*bv.y + a1.z*bv.z + a1.w*bv.w;
            }
        }
#pragma unroll
        for (int r = 0; r < 2; r++){
            float sn = sq[n0 + r];
#pragma unroll
            for (int i4 = 0; i4 < 8; i4 += 4){
                float4 dv;
                dv.x = sn - 2.0f*acc[r][i4+0] + sq[m0+i4+0];
                dv.y = sn - 2.0f*acc[r][i4+1] + sq[m0+i4+1];
                dv.z = sn - 2.0f*acc[r][i4+2] + sq[m0+i4+2];
                dv.w = sn - 2.0f*acc[r][i4+3] + sq[m0+i4+3];
                *(float4*)&dls[(n0+r)*64 + m0 + i4] = dv;
            }
        }
    }
    __syncthreads();
    for (int pr = 0; pr < 16; pr += 4){
        int n0 = w*16 + pr;
        unsigned long long c0 = (((unsigned long long)encf(dls[(n0+0)*64 + lane])) << 32) | (unsigned)lane;
        unsigned long long c1 = (((unsigned long long)encf(dls[(n0+1)*64 + lane])) << 32) | (unsigned)lane;
        unsigned long long c2 = (((unsigned long long)encf(dls[(n0+2)*64 + lane])) << 32) | (unsigned)lane;
        unsigned long long c3 = (((unsigned long long)encf(dls[(n0+3)*64 + lane])) << 32) | (unsigned)lane;
#pragma unroll
        for (int k = 2; k <= 64; k <<= 1){
#pragma unroll
            for (int j = k >> 1; j > 0; j >>= 1){
                bool keepmin = ((lane & j) == 0) == ((lane & k) == 0);
                unsigned long long o0 = __shfl_xor(c0, j, 64);
                unsigned long long o1 = __shfl_xor(c1, j, 64);
                unsigned long long o2 = __shfl_xor(c2, j, 64);
                unsigned long long o3 = __shfl_xor(c3, j, 64);
                c0 = keepmin ? (c0 < o0 ? c0 : o0) : (c0 < o0 ? o0 : c0);
                c1 = keepmin ? (c1 < o1 ? c1 : o1) : (c1 < o1 ? o1 : c1);
                c2 = keepmin ? (c2 < o2 ? c2 : o2) : (c2 < o2 ? o2 : c2);
                c3 = keepmin ? (c3 < o3 ? c3 : o3) : (c3 < o3 ? o3 : c3);
            }
        }
        if (lane >= 1 && lane <= KNB){
            int lb = n0*16 + lane - 1;
            int base = b*1024 + lb;
            int v0 = (int)(c0 & 0xffffffffu);
            int v1 = (int)(c1 & 0xffffffffu);
            int v2 = (int)(c2 & 0xffffffffu);
            int v3 = (int)(c3 & 0xffffffffu);
            idxg[base]      = v0; ils[lb]      = v0;
            idxg[base + 16] = v1; ils[lb + 16] = v1;
            idxg[base + 32] = v2; ils[lb + 32] = v2;
            idxg[base + 48] = v3; ils[lb + 48] = v3;
        }
    }
    const int KT = CIN/32;
    f16x8 ah[KT];
    {
        const float* xr = &xls[(w*16 + lrow)*CP];
#pragma unroll
        for (int kt = 0; kt < KT; kt++){
            union { f16x8 v; _Float16 u[8]; } H;
#pragma unroll
            for (int j = 0; j < 8; j++)
                H.u[j] = (_Float16)xr[kt*32 + lk*8 + j];
            ah[kt] = H.v;
        }
    }
    __syncthreads();
#pragma unroll
    for (int ct = 0; ct < CMID/16; ct++){
        int col = ct*16 + lrow;
        f32x4 aP = {0,0,0,0}, aQ = {0,0,0,0};
#pragma unroll
        for (int kt = 0; kt < KT; kt++){
            size_t bo = (size_t)col*CIN + kt*32 + lk*8;
            f16x8 bbh = *(const f16x8*)(wbh + bo);
            f16x8 bdh = *(const f16x8*)(wdh + bo);
            aP = __builtin_amdgcn_mfma_f32_16x16x32_f16(ah[kt], bbh, aP, 0, 0, 0);
            aQ = __builtin_amdgcn_mfma_f32_16x16x32_f16(ah[kt], bdh, aQ, 0, 0, 0);
        }
#pragma unroll
        for (int u = 0; u < 4; u++){
            int row = w*16 + lk*4 + u;
            size_t o = ((size_t)b*64 + row)*CMID + col;
            _Float16 hp = (_Float16)aP[u];
            _Float16 hq = (_Float16)aQ[u];
            P[o] = hp; Q[o] = hq;
            Pls[row*ASP + col] = hp;
            Qls[row*ASP + col] = hq;
        }
    }
    __syncthreads();
    {
        float s = 0.f, q = 0.f;
        for (int n = 0; n < 64; n++){
            float p = (float)Pls[n*ASP + t];
#pragma unroll 4
            for (int k = 0; k < 16; k++){
                int j = ils[n*16 + k];
                float v = p + (float)Qls[j*ASP + t];
                s += v; q += v*v;
            }
        }
        pS[(size_t)t*512 + b] = s;
        pQ[(size_t)t*512 + b] = q;
    }
}

// ---------------- mm2s: scaled 2-plane f16 MFMA (stages 1,2) -------------------
template<int CMID, int COUT, int NSET>
__global__ __launch_bounds__(256, 3)
void k_mm2s(const float* __restrict__ P, const float* __restrict__ Q,
            const int* __restrict__ idxg,
            const float* __restrict__ cA1, const float* __restrict__ cB1,
            const float* __restrict__ w2, const float* __restrict__ g2,
            unsigned* __restrict__ outenc,
            float* __restrict__ pS, float* __restrict__ pQ){
    const int AS = CMID + 8;
    const int NCOL = 64*NSET;
    const int NM = CMID/32;
    __shared__ __align__(16) _Float16 act_h[32*AS];
    __shared__ __align__(16) _Float16 act_m[32*AS];
    __shared__ unsigned maxtab[NCOL*65];
    __shared__ __align__(4) unsigned char ils8[1024];
    int t = threadIdx.x, b = blockIdx.x, cc = blockIdx.y;
    int lane = t & 63, w = t >> 6;
    int lrow = lane & 15, lk = lane >> 4;

    for (int i = t; i < 1024; i += 256) ils8[i] = (unsigned char)idxg[b*1024 + i];
    for (int i = t; i < NCOL*65; i += 256) maxtab[i] = ENC_NEGINF;

    int kq  = (t*4) & (CMID-1);
    int le0 = (t*4) / CMID;
    int PH  = (le0*NM) >> 4;
    float4 caq = *(const float4*)(cA1 + kq);
    float4 cbq = *(const float4*)(cB1 + kq);

    const int KT = CMID/32;
    f16x8 bh[NSET][KT], bm[NSET][KT];
    float sg[NSET];
    int ccBase = cc*NCOL;
#pragma unroll
    for (int s = 0; s < NSET; s++){
        int ncol = ccBase + s*64 + w*16 + lrow;
#pragma unroll
        for (int kt = 0; kt < KT; kt++){
            union { f16x8 v; _Float16 u[8]; } uh, um;
#pragma unroll
            for (int j = 0; j < 8; j++){
                int k = kt*32 + lk*8 + j;
                split2h(w2[(size_t)k*COUT + ncol], uh.u[j], um.u[j]);
            }
            bh[s][kt] = uh.v; bm[s][kt] = um.v;
        }
        sg[s] = (g2[ncol] < 0.0f) ? -1.0f : 1.0f;
    }
    float ss[NSET], qq[NSET];
#pragma unroll
    for (int s = 0; s < NSET; s++){ ss[s] = 0.f; qq[s] = 0.f; }
    const float* Pb = P + (size_t)b*64*CMID;
    const float* Qb = Q + (size_t)b*64*CMID;
    __syncthreads();

    unsigned jw;
    if (NM == 4) jw = *(const unsigned*)&ils8[le0*4];
    else         jw = *(const unsigned short*)&ils8[le0*2];
    float4 pv = *(const float4*)(Pb + PH*CMID + kq);
    float4 qvr[NM];
#pragma unroll
    for (int m = 0; m < NM; m++)
        qvr[m] = *(const float4*)(Qb + (size_t)((jw >> (8*m)) & 0xffu)*CMID + kq);

    for (int ch = 0; ch < 32; ch++){
#pragma unroll
        for (int m = 0; m < NM; m++){
            int le = le0*NM + m;
            float4 qv = qvr[m];
            float v0 = lrelu(caq.x*(pv.x + qv.x) + cbq.x);
            float v1 = lrelu(caq.y*(pv.y + qv.y) + cbq.y);
            float v2 = lrelu(caq.z*(pv.z + qv.z) + cbq.z);
            float v3 = lrelu(caq.w*(pv.w + qv.w) + cbq.w);
            union { f16x4 v; _Float16 u[4]; } hh, mm;
            split2h(v0, hh.u[0], mm.u[0]);
            split2h(v1, hh.u[1], mm.u[1]);
            split2h(v2, hh.u[2], mm.u[2]);
            split2h(v3, hh.u[3], mm.u[3]);
            *(f16x4*)&act_h[le*AS + kq] = hh.v;
            *(f16x4*)&act_m[le*AS + kq] = mm.v;
        }
        __syncthreads();

        if (ch < 31){
            if (NM == 4) jw = *(const unsigned*)&ils8[(ch+1)*32 + le0*4];
            else         jw = *(const unsigned short*)&ils8[(ch+1)*32 + le0*2];
            pv = *(const float4*)(Pb + (2*(ch+1) + PH)*CMID + kq);
#pragma unroll
            for (int m = 0; m < NM; m++)
                qvr[m] = *(const float4*)(Qb + (size_t)((jw >> (8*m)) & 0xffu)*CMID + kq);
        }
        int jj[2][4];
#pragma unroll
        for (int r = 0; r < 2; r++){
            unsigned wrd = *(const unsigned*)&ils8[ch*32 + r*16 + lk*4];
#pragma unroll
            for (int u = 0; u < 4; u++)
                jj[r][u] = (int)((wrd >> (8*u)) & 0xffu);
        }

        f32x4 accM[2][NSET], accC[2][NSET];
#pragma unroll
        for (int r = 0; r < 2; r++)
#pragma unroll
            for (int s = 0; s < NSET; s++){
                accM[r][s] = {0.f,0.f,0.f,0.f};
                accC[r][s] = {0.f,0.f,0.f,0.f};
            }
        __builtin_amdgcn_s_setprio(1);
#pragma unroll
        for (int kt = 0; kt < KT; kt++){
            int ko = kt*32 + lk*8;
#pragma unroll
            for (int r = 0; r < 2; r++){
                f16x8 ah = *(const f16x8*)&act_h[(r*16 + lrow)*AS + ko];
                f16x8 am = *(const f16x8*)&act_m[(r*16 + lrow)*AS + ko];
#pragma unroll
                for (int s = 0; s < NSET; s++){
                    accM[r][s] = __builtin_amdgcn_mfma_f32_16x16x32_f16(ah, bh[s][kt], accM[r][s], 0, 0, 0);
                    accC[r][s] = __builtin_amdgcn_mfma_f32_16x16x32_f16(ah, bm[s][kt], accC[r][s], 0, 0, 0);
                    accC[r][s] = __builtin_amdgcn_mfma_f32_16x16x32_f16(am, bh[s][kt], accC[r][s], 0, 0, 0);
                }
            }
        }
        __builtin_amdgcn_s_setprio(0);
#pragma unroll
        for (int r = 0; r < 2; r++){
#pragma unroll
            for (int s = 0; s < NSET; s++){
#pragma unroll
                for (int u = 0; u < 4; u++){
                    float v = accM[r][s][u] + accC[r][s][u]*(1.0f/2048.0f);
                    ss[s] += v; qq[s] += v*v;
                    int colL = s*64 + w*16 + lrow;
                    atomicMax(&maxtab[colL*65 + jj[r][u]], encf(sg[s]*v));
                }
            }
        }
        __syncthreads();
    }
#pragma unroll
    for (int s = 0; s < NSET; s++){
        ss[s] += __shfl_xor(ss[s], 16, 64); ss[s] += __shfl_xor(ss[s], 32, 64);
        qq[s] += __shfl_xor(qq[s], 16, 64); qq[s] += __shfl_xor(qq[s], 32, 64);
        if (lane < 16){
            pS[(size_t)(ccBase + s*64 + w*16 + lane)*512 + b] = ss[s];
            pQ[(size_t)(ccBase + s*64 + w*16 + lane)*512 + b] = qq[s];
        }
    }
    for (int i = t; i < 64*NCOL; i += 256){
        int colL = i % NCOL, j = i / NCOL;
        outenc[((size_t)b*64 + j)*COUT + ccBase + colL] = maxtab[colL*65 + j];
    }
}

// ---------------- mm2xh: f16 MFMA, packed-f16 act-build (stage 3) --------------
// Grid swapped to dim3(2, 512): cc=blockIdx.x, b=blockIdx.y -> the two blocks
// sharing batch b's P/Q are adjacent in dispatch order (L2 twin-sharing).
template<int CMID, int COUT, int NSET>
__global__ __launch_bounds__(256, 3)
void k_mm2xh(const _Float16* __restrict__ P, const _Float16* __restrict__ Q,
             const int* __restrict__ idxg,
             const float* __restrict__ cA1, const float* __restrict__ cB1,
             const float* __restrict__ w2, const float* __restrict__ g2,
             unsigned* __restrict__ outenc,
             float* __restrict__ pS, float* __restrict__ pQ){
    const int AS = CMID + 8;
    const int NCOL = 64*NSET;
    const int NM = CMID/64;
    __shared__ __align__(16) _Float16 act[32*AS];
    __shared__ unsigned maxtab[NCOL*65];
    __shared__ __align__(4) unsigned char ils8[1024];
    int t = threadIdx.x, b = blockIdx.y, cc = blockIdx.x;
    int lane = t & 63, w = t >> 6;
    int lrow = lane & 15, lk = lane >> 4;

    for (int i = t; i < 1024; i += 256) ils8[i] = (unsigned char)idxg[b*1024 + i];
    for (int i = t; i < NCOL*65; i += 256) maxtab[i] = ENC_NEGINF;

    int kq  = (t*8) & (CMID-1);
    int le0 = (t*8) / CMID;
    int PH  = (le0*NM) >> 4;
    union { f16x8 v; _Float16 u[8]; } cah, cbh;
#pragma unroll
    for (int j = 0; j < 8; j++){
        cah.u[j] = (_Float16)cA1[kq + j];
        cbh.u[j] = (_Float16)cB1[kq + j];
    }

    const int KT = CMID/32;
    f16x8 breg[NSET][KT];
    float sg[NSET];
    int ccBase = cc*NCOL;
#pragma unroll
    for (int s = 0; s < NSET; s++){
        int ncol = ccBase + s*64 + w*16 + lrow;
#pragma unroll
        for (int kt = 0; kt < KT; kt++){
            union { f16x8 v; _Float16 u[8]; } bu;
#pragma unroll
            for (int j = 0; j < 8; j++){
                int k = kt*32 + lk*8 + j;
                bu.u[j] = (_Float16)w2[(size_t)k*COUT + ncol];
            }
            breg[s][kt] = bu.v;
        }
        sg[s] = (g2[ncol] < 0.0f) ? -1.0f : 1.0f;
    }
    float ss[NSET], qq[NSET];
#pragma unroll
    for (int s = 0; s < NSET; s++){ ss[s] = 0.f; qq[s] = 0.f; }
    const _Float16* Pb = P + (size_t)b*64*CMID;
    const _Float16* Qb = Q + (size_t)b*64*CMID;
    __syncthreads();

    unsigned jw = *(const unsigned*)&ils8[le0*4];
    f16x8 pv = *(const f16x8*)(Pb + (size_t)PH*CMID + kq);
    f16x8 qvr[NM];
#pragma unroll
    for (int m = 0; m < NM; m++)
        qvr[m] = *(const f16x8*)(Qb + (size_t)((jw >> (8*m)) & 0xffu)*CMID + kq);

    for (int ch = 0; ch < 32; ch++){
#pragma unroll
        for (int m = 0; m < NM; m++){
            int le = le0*NM + m;
            f16x8 v = cah.v*(pv + qvr[m]) + cbh.v;
            f16x8 vm = v * (_Float16)0.2f;
#if __has_builtin(__builtin_elementwise_max)
            *(f16x8*)&act[le*AS + kq] = __builtin_elementwise_max(v, vm);
#else
            union { f16x8 x; _Float16 e8[8]; } V, M, R;
            V.x = v; M.x = vm;
#pragma unroll
            for (int u = 0; u < 8; u++)
                R.e8[u] = (V.e8[u] > (_Float16)0.0f) ? V.e8[u] : M.e8[u];
            *(f16x8*)&act[le*AS + kq] = R.x;
#endif
        }
        __syncthreads();

        if (ch < 31){
            jw = *(const unsigned*)&ils8[(ch+1)*32 + le0*4];
            pv = *(const f16x8*)(Pb + (size_t)(2*(ch+1) + PH)*CMID + kq);
#pragma unroll
            for (int m = 0; m < NM; m++)
                qvr[m] = *(const f16x8*)(Qb + (size_t)((jw >> (8*m)) & 0xffu)*CMID + kq);
        }
        int jj[2][4];
#pragma unroll
        for (int r = 0; r < 2; r++){
            unsigned wrd = *(const unsigned*)&ils8[ch*32 + r*16 + lk*4];
#pragma unroll
            for (int u = 0; u < 4; u++)
                jj[r][u] = (int)((wrd >> (8*u)) & 0xffu);
        }

        f32x4 acc[2][NSET];
#pragma unroll
        for (int r = 0; r < 2; r++)
#pragma unroll
            for (int s = 0; s < NSET; s++) acc[r][s] = {0.f,0.f,0.f,0.f};
        __builtin_amdgcn_s_setprio(1);
#pragma unroll
        for (int kt = 0; kt < KT; kt++){
            int ko = kt*32 + lk*8;
#pragma unroll
            for (int r = 0; r < 2; r++){
                f16x8 a = *(const f16x8*)&act[(r*16 + lrow)*AS + ko];
#pragma unroll
                for (int s = 0; s < NSET; s++)
                    acc[r][s] = __builtin_amdgcn_mfma_f32_16x16x32_f16(a, breg[s][kt], acc[r][s], 0, 0, 0);
            }
        }
        __builtin_amdgcn_s_setprio(0);
#pragma unroll
        for (int r = 0; r < 2; r++){
#pragma unroll
            for (int s = 0; s < NSET; s++){
#pragma unroll
                for (int u = 0; u < 4; u++){
                    float v = acc[r][s][u];
                    ss[s] += v; qq[s] += v*v;
                    int colL = s*64 + w*16 + lrow;
                    atomicMax(&maxtab[colL*65 + jj[r][u]], encf(sg[s]*v));
                }
            }
        }
        __syncthreads();
    }
#pragma unroll
    for (int s = 0; s < NSET; s++){
        ss[s] += __shfl_xor(ss[s], 16, 64); ss[s] += __shfl_xor(ss[s], 32, 64);
        qq[s] += __shfl_xor(qq[s], 16, 64); qq[s] += __shfl_xor(qq[s], 32, 64);
        if (lane < 16){
            pS[(size_t)(ccBase + s*64 + w*16 + lane)*512 + b] = ss[s];
            pQ[(size_t)(ccBase + s*64 + w*16 + lane)*512 + b] = qq[s];
        }
    }
    for (int i = t; i < 64*NCOL; i += 256){
        int colL = i % NCOL, j = i / NCOL;
        outenc[((size_t)b*64 + j)*COUT + ccBase + colL] = maxtab[colL*65 + j];
    }
}

// ---------------- pooling: LDS-staged coalesced reads, same reduce order -------
__global__ void k_pool(const unsigned* __restrict__ h1e, const unsigned* __restrict__ h2e,
                       const unsigned* __restrict__ h3e,
                       const float* __restrict__ cA1, const float* __restrict__ cB1,
                       const float* __restrict__ g1,
                       const float* __restrict__ cA2, const float* __restrict__ cB2,
                       const float* __restrict__ g2,
                       const float* __restrict__ cA3, const float* __restrict__ cB3,
                       const float* __restrict__ g3,
                       float* __restrict__ pooled){
    __shared__ __align__(16) unsigned tile[28672];   // h1[0:4096] h2[4096:12288] h3[12288:28672]
    int t = threadIdx.x, b = blockIdx.x;
    {
        const uint4* s1 = (const uint4*)(h1e + (size_t)b*4096);
        const uint4* s2 = (const uint4*)(h2e + (size_t)b*8192);
        const uint4* s3 = (const uint4*)(h3e + (size_t)b*16384);
        uint4* d = (uint4*)tile;
        for (int i = t; i < 1024; i += 256) d[i] = s1[i];
        for (int i = t; i < 2048; i += 256) d[1024 + i] = s2[i];
        for (int i = t; i < 4096; i += 256) d[3072 + i] = s3[i];
    }
    __syncthreads();
    for (int c = t; c < 448; c += 256){
        const unsigned* p; int C; float ca, cb, gv;
        if (c < 64){        p = &tile[c];              C = 64;  ca = cA1[c];     cb = cB1[c];     gv = g1[c]; }
        else if (c < 192){  p = &tile[4096 + (c-64)];  C = 128; ca = cA2[c-64];  cb = cB2[c-64];  gv = g2[c-64]; }
        else {              p = &tile[12288 + (c-192)];C = 256; ca = cA3[c-192]; cb = cB3[c-192]; gv = g3[c-192]; }
        float s = 0.f, mx = -INFINITY;
        for (int n = 0; n < 64; n++){
            float v = dec_ec(p[(size_t)n*C], ca, cb, gv);
            s += v; mx = fmaxf(mx, v);
        }
        pooled[b*896 + c] = s*(1.0f/64.0f);
        pooled[b*896 + 448 + c] = mx;
    }
}

// ---------------- classifier ----------------
#define FC1R 8
__global__ void k_fc1(const float* __restrict__ pooled, const float* __restrict__ w,
                      float* __restrict__ z, float* gs, float* gq){
    __shared__ float pls[FC1R*896];
    int r0 = blockIdx.x*FC1R;
    int co = blockIdx.y*256 + threadIdx.x;
    for (int i = threadIdx.x; i < FC1R*896; i += 256)
        pls[i] = pooled[(size_t)r0*896 + i];
    __syncthreads();
    float acc[FC1R];
#pragma unroll
    for (int rr = 0; rr < FC1R; rr++) acc[rr] = 0.f;
    for (int k = 0; k < 896; k++){
        float wv = w[(size_t)k*512 + co];
#pragma unroll
        for (int rr = 0; rr < FC1R; rr++)
            acc[rr] += pls[rr*896 + k]*wv;
    }
#pragma unroll
    for (int rr = 0; rr < FC1R; rr++){
        z[(size_t)(r0 + rr)*512 + co] = acc[rr];
        atomicAdd(&gs[co], acc[rr]);
        atomicAdd(&gq[co], acc[rr]*acc[rr]);
    }
}

// fc2 with fused flat BN-finalize head (identical formula to old k_bnfin)
__global__ void k_fc2(const float* __restrict__ z1,
                      const float* __restrict__ gs1, const float* __restrict__ gq1,
                      const float* __restrict__ g, const float* __restrict__ bb,
                      const float* __restrict__ w,
                      float* __restrict__ z2, float* gs, float* gq){
    __shared__ float cAl[512], cBl[512];
    for (int c = threadIdx.x; c < 512; c += 256){
        float m = gs1[c]*(1.0f/512);
        float v = gq1[c]*(1.0f/512) - m*m;
        v = v < 0.f ? 0.f : v;
        float a = g[c]*rsqrtf(v + EPSV);
        cAl[c] = a;
        cBl[c] = bb[c] - m*a;
    }
    __syncthreads();
    int r = blockIdx.x;
    int co = threadIdx.x;
    const float* zr = z1 + (size_t)r*512;
    float acc = 0.f;
    for (int k = 0; k < 512; k++){
        float v = lrelu(cAl[k]*zr[k] + cBl[k]);
        acc += v*w[(size_t)k*256 + co];
    }
    z2[(size_t)r*256 + co] = acc;
    atomicAdd(&gs[co], acc);
    atomicAdd(&gq[co], acc*acc);
}

// fc3 with fused flat BN-finalize head
__global__ void k_fc3(const float* __restrict__ z2,
                      const float* __restrict__ gs2, const float* __restrict__ gq2,
                      const float* __restrict__ g, const float* __restrict__ bb,
                      const float* __restrict__ w,
                      const float* __restrict__ bias, float* __restrict__ out){
    __shared__ float cAl[256], cBl[256];
    {
        int c = threadIdx.x;
        float m = gs2[c]*(1.0f/512);
        float v = gq2[c]*(1.0f/512) - m*m;
        v = v < 0.f ? 0.f : v;
        float a = g[c]*rsqrtf(v + EPSV);
        cAl[c] = a;
        cBl[c] = bb[c] - m*a;
    }
    __syncthreads();
    int r = blockIdx.x*256 + threadIdx.x;
    const float* zr = z2 + (size_t)r*256;
    float a0 = 0.f, a1 = 0.f;
    for (int k = 0; k < 256; k++){
        float v = lrelu(cAl[k]*zr[k] + cBl[k]);
        a0 += v*w[k*2 + 0];
        a1 += v*w[k*2 + 1];
    }
    out[r*2 + 0] = a0 + bias[0];
    out[r*2 + 1] = a1 + bias[1];
}

extern "C" void kernel_launch(void* const* d_in, const int* in_sizes, int n_in,
                              void* d_out, int out_size, void* d_ws, size_t ws_size,
                              hipStream_t stream){
    const float* x    = (const float*)d_in[0];
    const float* w_in = (const float*)d_in[2];
    const float* g_in = (const float*)d_in[3];
    const float* b_in = (const float*)d_in[4];
    const float* w1a  = (const float*)d_in[5];
    const float* g1a  = (const float*)d_in[6];
    const float* b1a  = (const float*)d_in[7];
    const float* w1b  = (const float*)d_in[8];
    const float* g1b  = (const float*)d_in[9];
    const float* b1b  = (const float*)d_in[10];
    const float* w2a  = (const float*)d_in[11];
    const float* g2a  = (const float*)d_in[12];
    const float* b2a  = (const float*)d_in[13];
    const float* w2b  = (const float*)d_in[14];
    const float* g2b  = (const float*)d_in[15];
    const float* b2b  = (const float*)d_in[16];
    const float* w3a  = (const float*)d_in[17];
    const float* g3a  = (const float*)d_in[18];
    const float* b3a  = (const float*)d_in[19];
    const float* w3b  = (const float*)d_in[20];
    const float* g3b  = (const float*)d_in[21];
    const float* b3b  = (const float*)d_in[22];
    const float* wc1  = (const float*)d_in[23];
    const float* gc1  = (const float*)d_in[24];
    const float* bc1  = (const float*)d_in[25];
    const float* wc2  = (const float*)d_in[26];
    const float* gc2  = (const float*)d_in[27];
    const float* bc2  = (const float*)d_in[28];
    const float* wc3  = (const float*)d_in[29];
    const float* bc3  = (const float*)d_in[30];

    char* ws = (char*)d_ws;
    size_t off = 0;
    auto alloc = [&](size_t bytes){
        size_t o = off; off = (off + bytes + 255) & ~(size_t)255; return o;
    };
    float* h0     = (float*)(ws + alloc((size_t)NPTS*64*4));
    float* h1     = (float*)(ws + alloc((size_t)NPTS*64*4));
    float* h2     = (float*)(ws + alloc((size_t)NPTS*128*4));
    float* h3     = (float*)(ws + alloc((size_t)NPTS*256*4));
    float* P      = (float*)(ws + alloc((size_t)NPTS*256*4));
    float* Q      = (float*)(ws + alloc((size_t)NPTS*256*4));
    int*   idx    = (int*)  (ws + alloc((size_t)NPTS*16*4));
    float* pooled = (float*)(ws + alloc((size_t)512*896*4));
    float* z1     = (float*)(ws + alloc((size_t)512*512*4));
    float* z2     = (float*)(ws + alloc((size_t)512*256*4));
    float* pS     = (float*)(ws + alloc((size_t)131072*4));
    float* pQ     = (float*)(ws + alloc((size_t)131072*4));
    float* stats  = (float*)(ws + alloc((size_t)2048*4));
    float* coefs  = (float*)(ws + alloc((size_t)3456*4));
    _Float16* wsp = (_Float16*)(ws + alloc((size_t)114688*2));

    _Float16 *w1bh = wsp,          *w1bm = wsp+4096,
             *w1dh = wsp+8192,     *w1dm = wsp+12288;           // stage1 64x64
    _Float16 *w2bh = wsp+16384,    *w2bm = wsp+24576,
             *w2dh = wsp+32768,    *w2dm = wsp+40960;           // stage2 64x128
    _Float16 *w3bh = wsp+49152,    *w3dh = wsp+81920;           // stage3 128x256

    float *f1s  = stats,       *f1q  = stats+512;
    float *f2s  = stats+1024,  *f2q  = stats+1280;
    float *cA0   = coefs,      *cB0   = coefs+64;
    float *cA1a  = coefs+128,  *cB1a  = coefs+192;
    float *cA1b  = coefs+256,  *cB1b  = coefs+320;
    float *cA2a  = coefs+384,  *cB2a  = coefs+512;
    float *cA2b  = coefs+640,  *cB2b  = coefs+768;
    float *cA3a  = coefs+896,  *cB3a  = coefs+1152;
    float *cA3b  = coefs+1408, *cB3b  = coefs+1664;

    (void)hipMemsetAsync(stats, 0, 2048*4, stream);

    // -------- weight prep (merged single launch) --------
    k_wprep_all<<<176, 256, 0, stream>>>(w1a, w2a, w3a,
                                         w1bh, w1bm, w1dh, w1dm,
                                         w2bh, w2bm, w2dh, w2dm,
                                         w3bh, w3dh);

    // -------- input MLP (h0 stays raw; ec1 decodes) --------
    k_input<<<NPTS/256, 256, 0, stream>>>(x, w_in, h0);
    k_colstats_part<<<64, 256, 0, stream>>>(h0, pS, pQ);
    k_bnfin_part<<<1, 64, 0, stream>>>(pS, pQ, g_in, b_in, cA0, cB0, 256, 1.0f/NPTS);

    // -------- edge conv 1 (64 -> 64/64); knn fused into ec1 --------
    k_ec1<64,64,0><<<BB, 256, 0, stream>>>(h0, cA0, cB0, nullptr,
                                           w1bh, w1bm, w1dh, w1dm, idx,
                                           P, Q, pS, pQ);
    k_bnfin_part<<<1, 64, 0, stream>>>(pS, pQ, g1a, b1a, cA1a, cB1a, 2048, 1.0f/NEDGE);
    k_mm2s<64,64,1><<<dim3(BB,1), 256, 0, stream>>>(P, Q, idx, cA1a, cB1a, w1b, g1b,
                                                    (unsigned*)h1, pS, pQ);
    k_bnfin_part<<<1, 64, 0, stream>>>(pS, pQ, g1b, b1b, cA1b, cB1b, 512, 1.0f/NEDGE);

    // -------- edge conv 2 (64 -> 128/128); h1 stays encoded --------
    k_ec1<64,128,1><<<BB, 256, 0, stream>>>(h1, cA1b, cB1b, g1b,
                                            w2bh, w2bm, w2dh, w2dm, idx,
                                            P, Q, pS, pQ);
    k_bnfin_part<<<1, 128, 0, stream>>>(pS, pQ, g2a, b2a, cA2a, cB2a, 1024, 1.0f/NEDGE);
    k_mm2s<128,128,2><<<dim3(BB,1), 256, 0, stream>>>(P, Q, idx, cA2a, cB2a, w2b, g2b,
                                                      (unsigned*)h2, pS, pQ);
    k_bnfin_part<<<1, 128, 0, stream>>>(pS, pQ, g2b, b2b, cA2b, cB2b, 512, 1.0f/NEDGE);

    // -------- edge conv 3 (128 -> 256/256); h2 stays encoded --------
    k_ec1h<128,256><<<BB, 256, 0, stream>>>((const unsigned*)h2, cA2b, cB2b, g2b,
                                            w3bh, w3dh, idx,
                                            (_Float16*)P, (_Float16*)Q, pS, pQ);
    k_bnfin_part<<<1, 256, 0, stream>>>(pS, pQ, g3a, b3a, cA3a, cB3a, 512, 1.0f/NEDGE);
    k_mm2xh<256,256,2><<<dim3(2,BB), 256, 0, stream>>>((_Float16*)P, (_Float16*)Q, idx,
                                                       cA3a, cB3a, w3b, g3b,
                                                       (unsigned*)h3, pS, pQ);
    k_bnfin_part<<<1, 256, 0, stream>>>(pS, pQ, g3b, b3b, cA3b, cB3b, 512, 1.0f/NEDGE);

    // -------- classifier (pool decodes all three encoded h's) --------
    k_pool<<<BB, 256, 0, stream>>>((const unsigned*)h1, (const unsigned*)h2,
                                   (const unsigned*)h3,
                                   cA1b, cB1b, g1b, cA2b, cB2b, g2b, cA3b, cB3b, g3b,
                                   pooled);
    k_fc1<<<dim3(512/FC1R, 2), 256, 0, stream>>>(pooled, wc1, z1, f1s, f1q);
    k_fc2<<<512, 256, 0, stream>>>(z1, f1s, f1q, gc1, bc1, wc2, z2, f2s, f2q);
    k_fc3<<<2, 256, 0, stream>>>(z2, f2s, f2q, gc2, bc2, wc3, bc3, (float*)d_out);

    (void)in_sizes; (void)n_in; (void)out_size; (void)ws_size;
}

// Round 12
// 1008.649 us; speedup vs baseline: 1.0498x; 1.0498x over previous
//
#include <hip/hip_runtime.h>
#include <hip/hip_fp16.h>
#include <math.h>

#define BB 512
#define NN 64
#define KNB 16
#define NPTS (BB*NN)        // 32768
#define NEDGE (BB*NN*KNB)   // 524288
#define EPSV 1e-5f

typedef __attribute__((ext_vector_type(8))) _Float16 f16x8;
typedef __attribute__((ext_vector_type(4))) _Float16 f16x4;
typedef __attribute__((ext_vector_type(4))) float f32x4;

__device__ __forceinline__ float lrelu(float x){ return fmaxf(x, 0.2f*x); }
__device__ __forceinline__ unsigned encf(float f){
    unsigned u = __float_as_uint(f);
    return (u & 0x80000000u) ? ~u : (u | 0x80000000u);
}
__device__ __forceinline__ float decf(unsigned e){
    unsigned u = (e & 0x80000000u) ? (e ^ 0x80000000u) : ~e;
    return __uint_as_float(u);
}
#define ENC_NEGINF 0x007FFFFFu   // encf(-inf)

__device__ __forceinline__ float dec_ec(unsigned e, float ca, float cb, float gv){
    if (e == ENC_NEGINF) return 0.0f;
    float s = (gv < 0.0f) ? -1.0f : 1.0f;
    return lrelu(ca*(s*decf(e)) + cb);
}

__device__ __forceinline__ void split2h(float v, _Float16& h, _Float16& m){
    h = (_Float16)v;
    float r = v - (float)h;
    m = (_Float16)(r * 2048.0f);
}

// ---------------- input MLP ----------------
__global__ void k_input(const float* __restrict__ x, const float* __restrict__ w,
                        float* __restrict__ h0){
    __shared__ float wls[6*64];
    int t = threadIdx.x;
    for (int i = t; i < 6*64; i += 256) wls[i] = w[i];
    __syncthreads();
    int row = blockIdx.x*256 + t;
    float xv[6];
#pragma unroll
    for (int k = 0; k < 6; k++) xv[k] = x[row*6 + k];
#pragma unroll 8
    for (int c = 0; c < 64; c++){
        float acc = 0.f;
#pragma unroll
        for (int k = 0; k < 6; k++) acc += xv[k]*wls[k*64 + c];
        h0[(size_t)row*64 + c] = acc;
    }
}

// ---- column stats, deterministic partials ----
__global__ void k_colstats_part(const float* __restrict__ h,
                                float* __restrict__ pS, float* __restrict__ pQ){
    int t = threadIdx.x;
    int c = t & 63;
    int g = t >> 6;
    int p = blockIdx.x*4 + g;
    const int rpb = NPTS/256;
    int r0 = p*rpb;
    float s = 0.f, q = 0.f;
    for (int r = r0; r < r0 + rpb; r++){
        float v = h[(size_t)r*64 + c];
        s += v; q += v*v;
    }
    pS[c*256 + p] = s;
    pQ[c*256 + p] = q;
}

// ---- BN finalize from partials (deterministic serial reduce) ----
__global__ void k_bnfin_part(const float* __restrict__ pS, const float* __restrict__ pQ,
                             const float* __restrict__ g, const float* __restrict__ b,
                             float* __restrict__ cA, float* __restrict__ cB,
                             int P, float invM){
    int c = threadIdx.x;
    const float* ps = pS + (size_t)c*P;
    const float* pq = pQ + (size_t)c*P;
    float s = 0.f, q = 0.f;
    for (int p = 0; p < P; p += 4){
        float4 vs = *(const float4*)(ps + p);
        float4 vq = *(const float4*)(pq + p);
        s += vs.x + vs.y + vs.z + vs.w;
        q += vq.x + vq.y + vq.z + vq.w;
    }
    float m = s*invM;
    float v = q*invM - m*m;
    v = v < 0.f ? 0.f : v;
    float a = g[c]*rsqrtf(v + EPSV);
    cA[c] = a;
    cB[c] = b[c] - m*a;
}

// ---- merged weight prep: all three stages in one launch (176 blocks) ----
__global__ void k_wprep_all(const float* __restrict__ w1a, const float* __restrict__ w2a,
                            const float* __restrict__ w3a,
                            _Float16* __restrict__ w1bh, _Float16* __restrict__ w1bm,
                            _Float16* __restrict__ w1dh, _Float16* __restrict__ w1dm,
                            _Float16* __restrict__ w2bh, _Float16* __restrict__ w2bm,
                            _Float16* __restrict__ w2dh, _Float16* __restrict__ w2dm,
                            _Float16* __restrict__ w3bh, _Float16* __restrict__ w3dh){
    int blk = blockIdx.x, t = threadIdx.x;
    if (blk < 16){
        const int CIN = 64, CMID = 64;
        int i = blk*256 + t;
        int k = i / CMID, c = i - k*CMID;
        float wb = w1a[(size_t)(CIN + k)*CMID + c];
        float wd = w1a[(size_t)k*CMID + c] - wb;
        size_t o = (size_t)c*CIN + k;
        _Float16 h, m;
        split2h(wb, h, m); w1bh[o] = h; w1bm[o] = m;
        split2h(wd, h, m); w1dh[o] = h; w1dm[o] = m;
    } else if (blk < 48){
        const int CIN = 64, CMID = 128;
        int i = (blk - 16)*256 + t;
        int k = i / CMID, c = i - k*CMID;
        float wb = w2a[(size_t)(CIN + k)*CMID + c];
        float wd = w2a[(size_t)k*CMID + c] - wb;
        size_t o = (size_t)c*CIN + k;
        _Float16 h, m;
        split2h(wb, h, m); w2bh[o] = h; w2bm[o] = m;
        split2h(wd, h, m); w2dh[o] = h; w2dm[o] = m;
    } else {
        const int CIN = 128, CMID = 256;
        int i = (blk - 48)*256 + t;
        int k = i / CMID, c = i - k*CMID;
        float wb = w3a[(size_t)(CIN + k)*CMID + c];
        float wd = w3a[(size_t)k*CMID + c] - wb;
        size_t o = (size_t)c*CIN + k;
        w3bh[o] = (_Float16)wb;
        w3dh[o] = (_Float16)wd;
    }
}

// ---- k_ec1: fused {decode -> knn -> P/Q GEMM -> edge stats} (stages 1,2) ------
template<int CIN, int CMID, int MODE>
__global__ __launch_bounds__(256)
void k_ec1(const void* __restrict__ xin,
           const float* __restrict__ cA, const float* __restrict__ cB,
           const float* __restrict__ g,
           const _Float16* __restrict__ wbh, const _Float16* __restrict__ wbm,
           const _Float16* __restrict__ wdh, const _Float16* __restrict__ wdm,
           int* __restrict__ idxg,
           float* __restrict__ P, float* __restrict__ Q,
           float* __restrict__ pS, float* __restrict__ pQ){
    const int CP  = CIN + 4;
    const int ASP = CMID + 9;
    constexpr int BA = 64*(CIN+4)*4 + 64*64*4 + 64*4;
    constexpr int BBY = 2*64*(CMID+9)*4;
    constexpr int UB = (BA > BBY) ? BA : BBY;
    __shared__ __align__(16) char ubuf[UB];
    __shared__ int ils[1024];
    float* xls = (float*)ubuf;
    float* dls = (float*)(ubuf + (size_t)64*CP*4);
    float* sq  = (float*)(ubuf + (size_t)64*CP*4 + (size_t)64*64*4);
    float* Pls = (float*)ubuf;
    float* Qls = (float*)(ubuf + (size_t)64*ASP*4);

    int t = threadIdx.x, b = blockIdx.x;
    int lane = t & 63, w = t >> 6;
    int lrow = lane & 15, lk = lane >> 4;

    if (MODE == 0){
        const float* xb = (const float*)xin + (size_t)b*64*CIN;
        for (int i = t; i < 64*CIN; i += 256){
            int n = i / CIN, c = i & (CIN-1);
            xls[n*CP + c] = lrelu(cA[c]*xb[i] + cB[c]);
        }
    } else {
        const unsigned* xb = (const unsigned*)xin + (size_t)b*64*CIN;
        for (int i = t; i < 64*CIN; i += 256){
            int n = i / CIN, c = i & (CIN-1);
            xls[n*CP + c] = dec_ec(xb[i], cA[c], cB[c], g[c]);
        }
    }
    __syncthreads();
    if (t < 64){
        float s = 0.f;
        for (int c = 0; c < CIN; c += 4){
            float4 v = *(const float4*)&xls[t*CP + c];
            s += v.x*v.x + v.y*v.y + v.z*v.z + v.w*v.w;
        }
        sq[t] = s;
    }
    __syncthreads();
    {
        int n0 = (t >> 3)*2;
        int m0 = (t & 7)*8;
        float acc[2][8];
#pragma unroll
        for (int r = 0; r < 2; r++)
#pragma unroll
            for (int i = 0; i < 8; i++) acc[r][i] = 0.f;
        const float* an0 = &xls[n0*CP];
        const float* an1 = &xls[(n0+1)*CP];
        const float* bm  = &xls[m0*CP];
        for (int c = 0; c < CIN; c += 4){
            float4 a0 = *(const float4*)(an0 + c);
            float4 a1 = *(const float4*)(an1 + c);
#pragma unroll
            for (int i = 0; i < 8; i++){
                float4 bv = *(const float4*)(bm + i*CP + c);
                acc[0][i] += a0.x*bv.x + a0.y*bv.y + a0.z*bv.z + a0.w*bv.w;
                acc[1][i] += a1.x*bv.x + a1.y*bv.y + a1.z*bv.z + a1.w*bv.w;
            }
        }
#pragma unroll
        for (int r = 0; r < 2; r++){
            float sn = sq[n0 + r];
#pragma unroll
            for (int i4 = 0; i4 < 8; i4 += 4){
                float4 dv;
                dv.x = sn - 2.0f*acc[r][i4+0] + sq[m0+i4+0];
                dv.y = sn - 2.0f*acc[r][i4+1] + sq[m0+i4+1];
                dv.z = sn - 2.0f*acc[r][i4+2] + sq[m0+i4+2];
                dv.w = sn - 2.0f*acc[r][i4+3] + sq[m0+i4+3];
                *(float4*)&dls[(n0+r)*64 + m0 + i4] = dv;
            }
        }
    }
    __syncthreads();
    for (int pr = 0; pr < 16; pr += 4){
        int n0 = w*16 + pr;
        unsigned long long c0 = (((unsigned long long)encf(dls[(n0+0)*64 + lane])) << 32) | (unsigned)lane;
        unsigned long long c1 = (((unsigned long long)encf(dls[(n0+1)*64 + lane])) << 32) | (unsigned)lane;
        unsigned long long c2 = (((unsigned long long)encf(dls[(n0+2)*64 + lane])) << 32) | (unsigned)lane;
        unsigned long long c3 = (((unsigned long long)encf(dls[(n0+3)*64 + lane])) << 32) | (unsigned)lane;
#pragma unroll
        for (int k = 2; k <= 64; k <<= 1){
#pragma unroll
            for (int j = k >> 1; j > 0; j >>= 1){
                bool keepmin = ((lane & j) == 0) == ((lane & k) == 0);
                unsigned long long o0 = __shfl_xor(c0, j, 64);
                unsigned long long o1 = __shfl_xor(c1, j, 64);
                unsigned long long o2 = __shfl_xor(c2, j, 64);
                unsigned long long o3 = __shfl_xor(c3, j, 64);
                c0 = keepmin ? (c0 < o0 ? c0 : o0) : (c0 < o0 ? o0 : c0);
                c1 = keepmin ? (c1 < o1 ? c1 : o1) : (c1 < o1 ? o1 : c1);
                c2 = keepmin ? (c2 < o2 ? c2 : o2) : (c2 < o2 ? o2 : c2);
                c3 = keepmin ? (c3 < o3 ? c3 : o3) : (c3 < o3 ? o3 : c3);
            }
        }
        if (lane >= 1 && lane <= KNB){
            int lb = n0*16 + lane - 1;
            int base = b*1024 + lb;
            int v0 = (int)(c0 & 0xffffffffu);
            int v1 = (int)(c1 & 0xffffffffu);
            int v2 = (int)(c2 & 0xffffffffu);
            int v3 = (int)(c3 & 0xffffffffu);
            idxg[base]      = v0; ils[lb]      = v0;
            idxg[base + 16] = v1; ils[lb + 16] = v1;
            idxg[base + 32] = v2; ils[lb + 32] = v2;
            idxg[base + 48] = v3; ils[lb + 48] = v3;
        }
    }
    const int KT = CIN/32;
    f16x8 ah[KT], am[KT];
    {
        const float* xr = &xls[(w*16 + lrow)*CP];
#pragma unroll
        for (int kt = 0; kt < KT; kt++){
            union { f16x8 v; _Float16 u[8]; } H, M;
#pragma unroll
            for (int j = 0; j < 8; j++)
                split2h(xr[kt*32 + lk*8 + j], H.u[j], M.u[j]);
            ah[kt] = H.v; am[kt] = M.v;
        }
    }
    __syncthreads();   // all xls/dls reads done before Pls/Qls overwrite
#pragma unroll
    for (int ct = 0; ct < CMID/16; ct++){
        int col = ct*16 + lrow;
        f32x4 aPM = {0,0,0,0}, aPC = {0,0,0,0};
        f32x4 aQM = {0,0,0,0}, aQC = {0,0,0,0};
#pragma unroll
        for (int kt = 0; kt < KT; kt++){
            size_t bo = (size_t)col*CIN + kt*32 + lk*8;
            f16x8 bbh = *(const f16x8*)(wbh + bo);
            f16x8 bbm = *(const f16x8*)(wbm + bo);
            f16x8 bdh = *(const f16x8*)(wdh + bo);
            f16x8 bdm = *(const f16x8*)(wdm + bo);
            aPM = __builtin_amdgcn_mfma_f32_16x16x32_f16(ah[kt], bbh, aPM, 0, 0, 0);
            aPC = __builtin_amdgcn_mfma_f32_16x16x32_f16(ah[kt], bbm, aPC, 0, 0, 0);
            aPC = __builtin_amdgcn_mfma_f32_16x16x32_f16(am[kt], bbh, aPC, 0, 0, 0);
            aQM = __builtin_amdgcn_mfma_f32_16x16x32_f16(ah[kt], bdh, aQM, 0, 0, 0);
            aQC = __builtin_amdgcn_mfma_f32_16x16x32_f16(ah[kt], bdm, aQC, 0, 0, 0);
            aQC = __builtin_amdgcn_mfma_f32_16x16x32_f16(am[kt], bdh, aQC, 0, 0, 0);
        }
#pragma unroll
        for (int u = 0; u < 4; u++){
            int row = w*16 + lk*4 + u;
            size_t o = ((size_t)b*64 + row)*CMID + col;
            float pv = aPM[u] + aPC[u]*(1.0f/2048.0f);
            float qv = aQM[u] + aQC[u]*(1.0f/2048.0f);
            P[o] = pv; Q[o] = qv;
            Pls[row*ASP + col] = pv;
            Qls[row*ASP + col] = qv;
        }
    }
    __syncthreads();
    {
        const int NG = 256/CMID;
        const int PT = 512*NG;
        const int NPG = 64/NG;
        int c  = t & (CMID-1);
        int gg = t / CMID;
        float s = 0.f, q = 0.f;
        for (int n = gg*NPG; n < (gg+1)*NPG; n++){
            float p = Pls[n*ASP + c];
#pragma unroll 4
            for (int k = 0; k < 16; k++){
                int j = ils[n*16 + k];
                float v = p + Qls[j*ASP + c];
                s += v; q += v*v;
            }
        }
        int p = b*NG + gg;
        pS[(size_t)c*PT + p] = s;
        pQ[(size_t)c*PT + p] = q;
    }
}

// ---- k_ec1h: fused {decode -> knn -> f16 GEMM -> stats} (stage 3) -------------
template<int CIN, int CMID>
__global__ __launch_bounds__(256)
void k_ec1h(const unsigned* __restrict__ xin,
            const float* __restrict__ cA, const float* __restrict__ cB,
            const float* __restrict__ g,
            const _Float16* __restrict__ wbh, const _Float16* __restrict__ wdh,
            int* __restrict__ idxg,
            _Float16* __restrict__ P, _Float16* __restrict__ Q,
            float* __restrict__ pS, float* __restrict__ pQ){
    const int CP  = CIN + 4;
    const int ASP = CMID + 9;
    constexpr int BA = 64*(CIN+4)*4 + 64*64*4 + 64*4;
    constexpr int BBY = 2*64*(CMID+9)*2;
    constexpr int UB = (BA > BBY) ? BA : BBY;
    __shared__ __align__(16) char ubuf[UB];
    __shared__ int ils[1024];
    float* xls = (float*)ubuf;
    float* dls = (float*)(ubuf + (size_t)64*CP*4);
    float* sq  = (float*)(ubuf + (size_t)64*CP*4 + (size_t)64*64*4);
    _Float16* Pls = (_Float16*)ubuf;
    _Float16* Qls = (_Float16*)(ubuf + (size_t)64*ASP*2);

    int t = threadIdx.x, b = blockIdx.x;
    int lane = t & 63, w = t >> 6;
    int lrow = lane & 15, lk = lane >> 4;

    {
        const unsigned* xb = xin + (size_t)b*64*CIN;
        for (int i = t; i < 64*CIN; i += 256){
            int n = i / CIN, c = i & (CIN-1);
            xls[n*CP + c] = dec_ec(xb[i], cA[c], cB[c], g[c]);
        }
    }
    __syncthreads();
    if (t < 64){
        float s = 0.f;
        for (int c = 0; c < CIN; c += 4){
            float4 v = *(const float4*)&xls[t*CP + c];
            s += v.x*v.x + v.y*v.y + v.z*v.z + v.w*v.w;
        }
        sq[t] = s;
    }
    __syncthreads();
    {
        int n0 = (t >> 3)*2;
        int m0 = (t & 7)*8;
        float acc[2][8];
#pragma unroll
        for (int r = 0; r < 2; r++)
#pragma unroll
            for (int i = 0; i < 8; i++) acc[r][i] = 0.f;
        const float* an0 = &xls[n0*CP];
        const float* an1 = &xls[(n0+1)*CP];
        const float* bm  = &xls[m0*CP];
        for (int c = 0; c < CIN; c += 4){
            float4 a0 = *(const float4*)(an0 + c);
            float4 a1 = *(const float4*)(an1 + c);
#pragma unroll
            for (int i = 0; i < 8; i++){
                float4 bv = *(const float4*)(bm + i*CP + c);
                acc[0][i] += a0.x*bv.x + a0.y*bv.y + a0.z*bv.z + a0.w*bv.w;
                acc[1][i] += a1.x*bv.x + a1.y*bv.y + a1.z*bv.z + a1.w*bv.w;
            }
        }
#pragma unroll
        for (int r = 0; r < 2; r++){
            float sn = sq[n0 + r];
#pragma unroll
            for (int i4 = 0; i4 < 8; i4 += 4){
                float4 dv;
                dv.x = sn - 2.0f*acc[r][i4+0] + sq[m0+i4+0];
                dv.y = sn - 2.0f*acc[r][i4+1] + sq[m0+i4+1];
                dv.z = sn - 2.0f*acc[r][i4+2] + sq[m0+i4+2];
                dv.w = sn - 2.0f*acc[r][i4+3] + sq[m0+i4+3];
                *(float4*)&dls[(n0+r)*64 + m0 + i4] = dv;
            }
        }
    }
    __syncthreads();
    for (int pr = 0; pr < 16; pr += 4){
        int n0 = w*16 + pr;
        unsigned long long c0 = (((unsigned long long)encf(dls[(n0+0)*64 + lane])) << 32) | (unsigned)lane;
        unsigned long long c1 = (((unsigned long long)encf(dls[(n0+1)*64 + lane])) << 32) | (unsigned)lane;
        unsigned long long c2 = (((unsigned long long)encf(dls[(n0+2)*64 + lane])) << 32) | (unsigned)lane;
        unsigned long long c3 = (((unsigned long long)encf(dls[(n0+3)*64 + lane])) << 32) | (unsigned)lane;
#pragma unroll
        for (int k = 2; k <= 64; k <<= 1){
#pragma unroll
            for (int j = k >> 1; j > 0; j >>= 1){
                bool keepmin = ((lane & j) == 0) == ((lane & k) == 0);
                unsigned long long o0 = __shfl_xor(c0, j, 64);
                unsigned long long o1 = __shfl_xor(c1, j, 64);
                unsigned long long o2 = __shfl_xor(c2, j, 64);
                unsigned long long o3 = __shfl_xor(c3, j, 64);
                c0 = keepmin ? (c0 < o0 ? c0 : o0) : (c0 < o0 ? o0 : c0);
                c1 = keepmin ? (c1 < o1 ? c1 : o1) : (c1 < o1 ? o1 : c1);
                c2 = keepmin ? (c2 < o2 ? c2 : o2) : (c2 < o2 ? o2 : c2);
                c3 = keepmin ? (c3 < o3 ? c3 : o3) : (c3 < o3 ? o3 : c3);
            }
        }
        if (lane >= 1 && lane <= KNB){
            int lb = n0*16 + lane - 1;
            int base = b*1024 + lb;
            int v0 = (int)(c0 & 0xffffffffu);
            int v1 = (int)(c1 & 0xffffffffu);
            int v2 = (int)(c2 & 0xffffffffu);
            int v3 = (int)(c3 & 0xffffffffu);
            idxg[base]      = v0; ils[lb]      = v0;
            idxg[base + 16] = v1; ils[lb + 16] = v1;
            idxg[base + 32] = v2; ils[lb + 32] = v2;
            idxg[base + 48] = v3; ils[lb + 48] = v3;
        }
    }
    const int KT = CIN/32;
    f16x8 ah[KT];
    {
        const float* xr = &xls[(w*16 + lrow)*CP];
#pragma unroll
        for (int kt = 0; kt < KT; kt++){
            union { f16x8 v; _Float16 u[8]; } H;
#pragma unroll
            for (int j = 0; j < 8; j++)
                H.u[j] = (_Float16)xr[kt*32 + lk*8 + j];
            ah[kt] = H.v;
        }
    }
    __syncthreads();
#pragma unroll
    for (int ct = 0; ct < CMID/16; ct++){
        int col = ct*16 + lrow;
        f32x4 aP = {0,0,0,0}, aQ = {0,0,0,0};
#pragma unroll
        for (int kt = 0; kt < KT; kt++){
            size_t bo = (size_t)col*CIN + kt*32 + lk*8;
            f16x8 bbh = *(const f16x8*)(wbh + bo);
            f16x8 bdh = *(const f16x8*)(wdh + bo);
            aP = __builtin_amdgcn_mfma_f32_16x16x32_f16(ah[kt], bbh, aP, 0, 0, 0);
            aQ = __builtin_amdgcn_mfma_f32_16x16x32_f16(ah[kt], bdh, aQ, 0, 0, 0);
        }
#pragma unroll
        for (int u = 0; u < 4; u++){
            int row = w*16 + lk*4 + u;
            size_t o = ((size_t)b*64 + row)*CMID + col;
            _Float16 hp = (_Float16)aP[u];
            _Float16 hq = (_Float16)aQ[u];
            P[o] = hp; Q[o] = hq;
            Pls[row*ASP + col] = hp;
            Qls[row*ASP + col] = hq;
        }
    }
    __syncthreads();
    {
        float s = 0.f, q = 0.f;
        for (int n = 0; n < 64; n++){
            float p = (float)Pls[n*ASP + t];
#pragma unroll 4
            for (int k = 0; k < 16; k++){
                int j = ils[n*16 + k];
                float v = p + (float)Qls[j*ASP + t];
                s += v; q += v*v;
            }
        }
        pS[(size_t)t*512 + b] = s;
        pQ[(size_t)t*512 + b] = q;
    }
}

// ---------------- mm2s: scaled 2-plane f16 MFMA (stages 1,2) -------------------
template<int CMID, int COUT, int NSET>
__global__ __launch_bounds__(256, 3)
void k_mm2s(const float* __restrict__ P, const float* __restrict__ Q,
            const int* __restrict__ idxg,
            const float* __restrict__ cA1, const float* __restrict__ cB1,
            const float* __restrict__ w2, const float* __restrict__ g2,
            unsigned* __restrict__ outenc,
            float* __restrict__ pS, float* __restrict__ pQ){
    const int AS = CMID + 8;
    const int NCOL = 64*NSET;
    const int NM = CMID/32;
    __shared__ __align__(16) _Float16 act_h[32*AS];
    __shared__ __align__(16) _Float16 act_m[32*AS];
    __shared__ unsigned maxtab[NCOL*65];
    __shared__ __align__(4) unsigned char ils8[1024];
    int t = threadIdx.x, b = blockIdx.x, cc = blockIdx.y;
    int lane = t & 63, w = t >> 6;
    int lrow = lane & 15, lk = lane >> 4;

    for (int i = t; i < 1024; i += 256) ils8[i] = (unsigned char)idxg[b*1024 + i];
    for (int i = t; i < NCOL*65; i += 256) maxtab[i] = ENC_NEGINF;

    int kq  = (t*4) & (CMID-1);
    int le0 = (t*4) / CMID;
    int PH  = (le0*NM) >> 4;
    float4 caq = *(const float4*)(cA1 + kq);
    float4 cbq = *(const float4*)(cB1 + kq);

    const int KT = CMID/32;
    f16x8 bh[NSET][KT], bm[NSET][KT];
    float sg[NSET];
    int ccBase = cc*NCOL;
#pragma unroll
    for (int s = 0; s < NSET; s++){
        int ncol = ccBase + s*64 + w*16 + lrow;
#pragma unroll
        for (int kt = 0; kt < KT; kt++){
            union { f16x8 v; _Float16 u[8]; } uh, um;
#pragma unroll
            for (int j = 0; j < 8; j++){
                int k = kt*32 + lk*8 + j;
                split2h(w2[(size_t)k*COUT + ncol], uh.u[j], um.u[j]);
            }
            bh[s][kt] = uh.v; bm[s][kt] = um.v;
        }
        sg[s] = (g2[ncol] < 0.0f) ? -1.0f : 1.0f;
    }
    float ss[NSET], qq[NSET];
#pragma unroll
    for (int s = 0; s < NSET; s++){ ss[s] = 0.f; qq[s] = 0.f; }
    const float* Pb = P + (size_t)b*64*CMID;
    const float* Qb = Q + (size_t)b*64*CMID;
    __syncthreads();

    unsigned jw;
    if (NM == 4) jw = *(const unsigned*)&ils8[le0*4];
    else         jw = *(const unsigned short*)&ils8[le0*2];
    float4 pv = *(const float4*)(Pb + PH*CMID + kq);
    float4 qvr[NM];
#pragma unroll
    for (int m = 0; m < NM; m++)
        qvr[m] = *(const float4*)(Qb + (size_t)((jw >> (8*m)) & 0xffu)*CMID + kq);

    for (int ch = 0; ch < 32; ch++){
#pragma unroll
        for (int m = 0; m < NM; m++){
            int le = le0*NM + m;
            float4 qv = qvr[m];
            float v0 = lrelu(caq.x*(pv.x + qv.x) + cbq.x);
            float v1 = lrelu(caq.y*(pv.y + qv.y) + cbq.y);
            float v2 = lrelu(caq.z*(pv.z + qv.z) + cbq.z);
            float v3 = lrelu(caq.w*(pv.w + qv.w) + cbq.w);
            union { f16x4 v; _Float16 u[4]; } hh, mm;
            split2h(v0, hh.u[0], mm.u[0]);
            split2h(v1, hh.u[1], mm.u[1]);
            split2h(v2, hh.u[2], mm.u[2]);
            split2h(v3, hh.u[3], mm.u[3]);
            *(f16x4*)&act_h[le*AS + kq] = hh.v;
            *(f16x4*)&act_m[le*AS + kq] = mm.v;
        }
        __syncthreads();

        if (ch < 31){
            if (NM == 4) jw = *(const unsigned*)&ils8[(ch+1)*32 + le0*4];
            else         jw = *(const unsigned short*)&ils8[(ch+1)*32 + le0*2];
            pv = *(const float4*)(Pb + (2*(ch+1) + PH)*CMID + kq);
#pragma unroll
            for (int m = 0; m < NM; m++)
                qvr[m] = *(const float4*)(Qb + (size_t)((jw >> (8*m)) & 0xffu)*CMID + kq);
        }
        int jj[2][4];
#pragma unroll
        for (int r = 0; r < 2; r++){
            unsigned wrd = *(const unsigned*)&ils8[ch*32 + r*16 + lk*4];
#pragma unroll
            for (int u = 0; u < 4; u++)
                jj[r][u] = (int)((wrd >> (8*u)) & 0xffu);
        }

        f32x4 accM[2][NSET], accC[2][NSET];
#pragma unroll
        for (int r = 0; r < 2; r++)
#pragma unroll
            for (int s = 0; s < NSET; s++){
                accM[r][s] = {0.f,0.f,0.f,0.f};
                accC[r][s] = {0.f,0.f,0.f,0.f};
            }
        __builtin_amdgcn_s_setprio(1);
#pragma unroll
        for (int kt = 0; kt < KT; kt++){
            int ko = kt*32 + lk*8;
#pragma unroll
            for (int r = 0; r < 2; r++){
                f16x8 ah = *(const f16x8*)&act_h[(r*16 + lrow)*AS + ko];
                f16x8 am = *(const f16x8*)&act_m[(r*16 + lrow)*AS + ko];
#pragma unroll
                for (int s = 0; s < NSET; s++){
                    accM[r][s] = __builtin_amdgcn_mfma_f32_16x16x32_f16(ah, bh[s][kt], accM[r][s], 0, 0, 0);
                    accC[r][s] = __builtin_amdgcn_mfma_f32_16x16x32_f16(ah, bm[s][kt], accC[r][s], 0, 0, 0);
                    accC[r][s] = __builtin_amdgcn_mfma_f32_16x16x32_f16(am, bh[s][kt], accC[r][s], 0, 0, 0);
                }
            }
        }
        __builtin_amdgcn_s_setprio(0);
#pragma unroll
        for (int r = 0; r < 2; r++){
#pragma unroll
            for (int s = 0; s < NSET; s++){
#pragma unroll
                for (int u = 0; u < 4; u++){
                    float v = accM[r][s][u] + accC[r][s][u]*(1.0f/2048.0f);
                    ss[s] += v; qq[s] += v*v;
                    int colL = s*64 + w*16 + lrow;
                    atomicMax(&maxtab[colL*65 + jj[r][u]], encf(sg[s]*v));
                }
            }
        }
        __syncthreads();
    }
#pragma unroll
    for (int s = 0; s < NSET; s++){
        ss[s] += __shfl_xor(ss[s], 16, 64); ss[s] += __shfl_xor(ss[s], 32, 64);
        qq[s] += __shfl_xor(qq[s], 16, 64); qq[s] += __shfl_xor(qq[s], 32, 64);
        if (lane < 16){
            pS[(size_t)(ccBase + s*64 + w*16 + lane)*512 + b] = ss[s];
            pQ[(size_t)(ccBase + s*64 + w*16 + lane)*512 + b] = qq[s];
        }
    }
    for (int i = t; i < 64*NCOL; i += 256){
        int colL = i % NCOL, j = i / NCOL;
        outenc[((size_t)b*64 + j)*COUT + ccBase + colL] = maxtab[colL*65 + j];
    }
}

// ---------------- mm2xh: f16 MFMA, packed-f16 act-build (stage 3) --------------
template<int CMID, int COUT, int NSET>
__global__ __launch_bounds__(256, 3)
void k_mm2xh(const _Float16* __restrict__ P, const _Float16* __restrict__ Q,
             const int* __restrict__ idxg,
             const float* __restrict__ cA1, const float* __restrict__ cB1,
             const float* __restrict__ w2, const float* __restrict__ g2,
             unsigned* __restrict__ outenc,
             float* __restrict__ pS, float* __restrict__ pQ){
    const int AS = CMID + 8;
    const int NCOL = 64*NSET;
    const int NM = CMID/64;
    __shared__ __align__(16) _Float16 act[32*AS];
    __shared__ unsigned maxtab[NCOL*65];
    __shared__ __align__(4) unsigned char ils8[1024];
    int t = threadIdx.x, b = blockIdx.x, cc = blockIdx.y;
    int lane = t & 63, w = t >> 6;
    int lrow = lane & 15, lk = lane >> 4;

    for (int i = t; i < 1024; i += 256) ils8[i] = (unsigned char)idxg[b*1024 + i];
    for (int i = t; i < NCOL*65; i += 256) maxtab[i] = ENC_NEGINF;

    int kq  = (t*8) & (CMID-1);
    int le0 = (t*8) / CMID;
    int PH  = (le0*NM) >> 4;
    union { f16x8 v; _Float16 u[8]; } cah, cbh;
#pragma unroll
    for (int j = 0; j < 8; j++){
        cah.u[j] = (_Float16)cA1[kq + j];
        cbh.u[j] = (_Float16)cB1[kq + j];
    }

    const int KT = CMID/32;
    f16x8 breg[NSET][KT];
    float sg[NSET];
    int ccBase = cc*NCOL;
#pragma unroll
    for (int s = 0; s < NSET; s++){
        int ncol = ccBase + s*64 + w*16 + lrow;
#pragma unroll
        for (int kt = 0; kt < KT; kt++){
            union { f16x8 v; _Float16 u[8]; } bu;
#pragma unroll
            for (int j = 0; j < 8; j++){
                int k = kt*32 + lk*8 + j;
                bu.u[j] = (_Float16)w2[(size_t)k*COUT + ncol];
            }
            breg[s][kt] = bu.v;
        }
        sg[s] = (g2[ncol] < 0.0f) ? -1.0f : 1.0f;
    }
    float ss[NSET], qq[NSET];
#pragma unroll
    for (int s = 0; s < NSET; s++){ ss[s] = 0.f; qq[s] = 0.f; }
    const _Float16* Pb = P + (size_t)b*64*CMID;
    const _Float16* Qb = Q + (size_t)b*64*CMID;
    __syncthreads();

    unsigned jw = *(const unsigned*)&ils8[le0*4];
    f16x8 pv = *(const f16x8*)(Pb + (size_t)PH*CMID + kq);
    f16x8 qvr[NM];
#pragma unroll
    for (int m = 0; m < NM; m++)
        qvr[m] = *(const f16x8*)(Qb + (size_t)((jw >> (8*m)) & 0xffu)*CMID + kq);

    for (int ch = 0; ch < 32; ch++){
#pragma unroll
        for (int m = 0; m < NM; m++){
            int le = le0*NM + m;
            f16x8 v = cah.v*(pv + qvr[m]) + cbh.v;
            f16x8 vm = v * (_Float16)0.2f;
#if __has_builtin(__builtin_elementwise_max)
            *(f16x8*)&act[le*AS + kq] = __builtin_elementwise_max(v, vm);
#else
            union { f16x8 x; _Float16 e8[8]; } V, M, R;
            V.x = v; M.x = vm;
#pragma unroll
            for (int u = 0; u < 8; u++)
                R.e8[u] = (V.e8[u] > (_Float16)0.0f) ? V.e8[u] : M.e8[u];
            *(f16x8*)&act[le*AS + kq] = R.x;
#endif
        }
        __syncthreads();

        if (ch < 31){
            jw = *(const unsigned*)&ils8[(ch+1)*32 + le0*4];
            pv = *(const f16x8*)(Pb + (size_t)(2*(ch+1) + PH)*CMID + kq);
#pragma unroll
            for (int m = 0; m < NM; m++)
                qvr[m] = *(const f16x8*)(Qb + (size_t)((jw >> (8*m)) & 0xffu)*CMID + kq);
        }
        int jj[2][4];
#pragma unroll
        for (int r = 0; r < 2; r++){
            unsigned wrd = *(const unsigned*)&ils8[ch*32 + r*16 + lk*4];
#pragma unroll
            for (int u = 0; u < 4; u++)
                jj[r][u] = (int)((wrd >> (8*u)) & 0xffu);
        }

        f32x4 acc[2][NSET];
#pragma unroll
        for (int r = 0; r < 2; r++)
#pragma unroll
            for (int s = 0; s < NSET; s++) acc[r][s] = {0.f,0.f,0.f,0.f};
        __builtin_amdgcn_s_setprio(1);
#pragma unroll
        for (int kt = 0; kt < KT; kt++){
            int ko = kt*32 + lk*8;
#pragma unroll
            for (int r = 0; r < 2; r++){
                f16x8 a = *(const f16x8*)&act[(r*16 + lrow)*AS + ko];
#pragma unroll
                for (int s = 0; s < NSET; s++)
                    acc[r][s] = __builtin_amdgcn_mfma_f32_16x16x32_f16(a, breg[s][kt], acc[r][s], 0, 0, 0);
            }
        }
        __builtin_amdgcn_s_setprio(0);
#pragma unroll
        for (int r = 0; r < 2; r++){
#pragma unroll
            for (int s = 0; s < NSET; s++){
#pragma unroll
                for (int u = 0; u < 4; u++){
                    float v = acc[r][s][u];
                    ss[s] += v; qq[s] += v*v;
                    int colL = s*64 + w*16 + lrow;
                    atomicMax(&maxtab[colL*65 + jj[r][u]], encf(sg[s]*v));
                }
            }
        }
        __syncthreads();
    }
#pragma unroll
    for (int s = 0; s < NSET; s++){
        ss[s] += __shfl_xor(ss[s], 16, 64); ss[s] += __shfl_xor(ss[s], 32, 64);
        qq[s] += __shfl_xor(qq[s], 16, 64); qq[s] += __shfl_xor(qq[s], 32, 64);
        if (lane < 16){
            pS[(size_t)(ccBase + s*64 + w*16 + lane)*512 + b] = ss[s];
            pQ[(size_t)(ccBase + s*64 + w*16 + lane)*512 + b] = qq[s];
        }
    }
    for (int i = t; i < 64*NCOL; i += 256){
        int colL = i % NCOL, j = i / NCOL;
        outenc[((size_t)b*64 + j)*COUT + ccBase + colL] = maxtab[colL*65 + j];
    }
}

// ---------------- pooling: LDS-staged coalesced reads, same reduce order -------
__global__ void k_pool(const unsigned* __restrict__ h1e, const unsigned* __restrict__ h2e,
                       const unsigned* __restrict__ h3e,
                       const float* __restrict__ cA1, const float* __restrict__ cB1,
                       const float* __restrict__ g1,
                       const float* __restrict__ cA2, const float* __restrict__ cB2,
                       const float* __restrict__ g2,
                       const float* __restrict__ cA3, const float* __restrict__ cB3,
                       const float* __restrict__ g3,
                       float* __restrict__ pooled){
    __shared__ __align__(16) unsigned tile[28672];   // h1[0:4096] h2[4096:12288] h3[12288:28672]
    int t = threadIdx.x, b = blockIdx.x;
    {
        const uint4* s1 = (const uint4*)(h1e + (size_t)b*4096);
        const uint4* s2 = (const uint4*)(h2e + (size_t)b*8192);
        const uint4* s3 = (const uint4*)(h3e + (size_t)b*16384);
        uint4* d = (uint4*)tile;
        for (int i = t; i < 1024; i += 256) d[i] = s1[i];
        for (int i = t; i < 2048; i += 256) d[1024 + i] = s2[i];
        for (int i = t; i < 4096; i += 256) d[3072 + i] = s3[i];
    }
    __syncthreads();
    for (int c = t; c < 448; c += 256){
        const unsigned* p; int C; float ca, cb, gv;
        if (c < 64){        p = &tile[c];              C = 64;  ca = cA1[c];     cb = cB1[c];     gv = g1[c]; }
        else if (c < 192){  p = &tile[4096 + (c-64)];  C = 128; ca = cA2[c-64];  cb = cB2[c-64];  gv = g2[c-64]; }
        else {              p = &tile[12288 + (c-192)];C = 256; ca = cA3[c-192]; cb = cB3[c-192]; gv = g3[c-192]; }
        float s = 0.f, mx = -INFINITY;
        for (int n = 0; n < 64; n++){
            float v = dec_ec(p[(size_t)n*C], ca, cb, gv);
            s += v; mx = fmaxf(mx, v);
        }
        pooled[b*896 + c] = s*(1.0f/64.0f);
        pooled[b*896 + 448 + c] = mx;
    }
}

// ---------------- classifier ----------------
#define FC1R 8
__global__ void k_fc1(const float* __restrict__ pooled, const float* __restrict__ w,
                      float* __restrict__ z, float* gs, float* gq){
    __shared__ float pls[FC1R*896];
    int r0 = blockIdx.x*FC1R;
    int co = blockIdx.y*256 + threadIdx.x;
    for (int i = threadIdx.x; i < FC1R*896; i += 256)
        pls[i] = pooled[(size_t)r0*896 + i];
    __syncthreads();
    float acc[FC1R];
#pragma unroll
    for (int rr = 0; rr < FC1R; rr++) acc[rr] = 0.f;
    for (int k = 0; k < 896; k++){
        float wv = w[(size_t)k*512 + co];
#pragma unroll
        for (int rr = 0; rr < FC1R; rr++)
            acc[rr] += pls[rr*896 + k]*wv;
    }
#pragma unroll
    for (int rr = 0; rr < FC1R; rr++){
        z[(size_t)(r0 + rr)*512 + co] = acc[rr];
        atomicAdd(&gs[co], acc[rr]);
        atomicAdd(&gq[co], acc[rr]*acc[rr]);
    }
}

// fc2 with fused flat BN-finalize head (identical formula to old k_bnfin)
__global__ void k_fc2(const float* __restrict__ z1,
                      const float* __restrict__ gs1, const float* __restrict__ gq1,
                      const float* __restrict__ g, const float* __restrict__ bb,
                      const float* __restrict__ w,
                      float* __restrict__ z2, float* gs, float* gq){
    __shared__ float cAl[512], cBl[512];
    for (int c = threadIdx.x; c < 512; c += 256){
        float m = gs1[c]*(1.0f/512);
        float v = gq1[c]*(1.0f/512) - m*m;
        v = v < 0.f ? 0.f : v;
        float a = g[c]*rsqrtf(v + EPSV);
        cAl[c] = a;
        cBl[c] = bb[c] - m*a;
    }
    __syncthreads();
    int r = blockIdx.x;
    int co = threadIdx.x;
    const float* zr = z1 + (size_t)r*512;
    float acc = 0.f;
    for (int k = 0; k < 512; k++){
        float v = lrelu(cAl[k]*zr[k] + cBl[k]);
        acc += v*w[(size_t)k*256 + co];
    }
    z2[(size_t)r*256 + co] = acc;
    atomicAdd(&gs[co], acc);
    atomicAdd(&gq[co], acc*acc);
}

// fc3 with fused flat BN-finalize head
__global__ void k_fc3(const float* __restrict__ z2,
                      const float* __restrict__ gs2, const float* __restrict__ gq2,
                      const float* __restrict__ g, const float* __restrict__ bb,
                      const float* __restrict__ w,
                      const float* __restrict__ bias, float* __restrict__ out){
    __shared__ float cAl[256], cBl[256];
    {
        int c = threadIdx.x;
        float m = gs2[c]*(1.0f/512);
        float v = gq2[c]*(1.0f/512) - m*m;
        v = v < 0.f ? 0.f : v;
        float a = g[c]*rsqrtf(v + EPSV);
        cAl[c] = a;
        cBl[c] = bb[c] - m*a;
    }
    __syncthreads();
    int r = blockIdx.x*256 + threadIdx.x;
    const float* zr = z2 + (size_t)r*256;
    float a0 = 0.f, a1 = 0.f;
    for (int k = 0; k < 256; k++){
        float v = lrelu(cAl[k]*zr[k] + cBl[k]);
        a0 += v*w[k*2 + 0];
        a1 += v*w[k*2 + 1];
    }
    out[r*2 + 0] = a0 + bias[0];
    out[r*2 + 1] = a1 + bias[1];
}

extern "C" void kernel_launch(void* const* d_in, const int* in_sizes, int n_in,
                              void* d_out, int out_size, void* d_ws, size_t ws_size,
                              hipStream_t stream){
    const float* x    = (const float*)d_in[0];
    const float* w_in = (const float*)d_in[2];
    const float* g_in = (const float*)d_in[3];
    const float* b_in = (const float*)d_in[4];
    const float* w1a  = (const float*)d_in[5];
    const float* g1a  = (const float*)d_in[6];
    const float* b1a  = (const float*)d_in[7];
    const float* w1b  = (const float*)d_in[8];
    const float* g1b  = (const float*)d_in[9];
    const float* b1b  = (const float*)d_in[10];
    const float* w2a  = (const float*)d_in[11];
    const float* g2a  = (const float*)d_in[12];
    const float* b2a  = (const float*)d_in[13];
    const float* w2b  = (const float*)d_in[14];
    const float* g2b  = (const float*)d_in[15];
    const float* b2b  = (const float*)d_in[16];
    const float* w3a  = (const float*)d_in[17];
    const float* g3a  = (const float*)d_in[18];
    const float* b3a  = (const float*)d_in[19];
    const float* w3b  = (const float*)d_in[20];
    const float* g3b  = (const float*)d_in[21];
    const float* b3b  = (const float*)d_in[22];
    const float* wc1  = (const float*)d_in[23];
    const float* gc1  = (const float*)d_in[24];
    const float* bc1  = (const float*)d_in[25];
    const float* wc2  = (const float*)d_in[26];
    const float* gc2  = (const float*)d_in[27];
    const float* bc2  = (const float*)d_in[28];
    const float* wc3  = (const float*)d_in[29];
    const float* bc3  = (const float*)d_in[30];

    char* ws = (char*)d_ws;
    size_t off = 0;
    auto alloc = [&](size_t bytes){
        size_t o = off; off = (off + bytes + 255) & ~(size_t)255; return o;
    };
    float* h0     = (float*)(ws + alloc((size_t)NPTS*64*4));
    float* h1     = (float*)(ws + alloc((size_t)NPTS*64*4));
    float* h2     = (float*)(ws + alloc((size_t)NPTS*128*4));
    float* h3     = (float*)(ws + alloc((size_t)NPTS*256*4));
    float* P      = (float*)(ws + alloc((size_t)NPTS*256*4));
    float* Q      = (float*)(ws + alloc((size_t)NPTS*256*4));
    int*   idx    = (int*)  (ws + alloc((size_t)NPTS*16*4));
    float* pooled = (float*)(ws + alloc((size_t)512*896*4));
    float* z1     = (float*)(ws + alloc((size_t)512*512*4));
    float* z2     = (float*)(ws + alloc((size_t)512*256*4));
    float* pS     = (float*)(ws + alloc((size_t)131072*4));
    float* pQ     = (float*)(ws + alloc((size_t)131072*4));
    float* stats  = (float*)(ws + alloc((size_t)2048*4));
    float* coefs  = (float*)(ws + alloc((size_t)3456*4));
    _Float16* wsp = (_Float16*)(ws + alloc((size_t)114688*2));

    _Float16 *w1bh = wsp,          *w1bm = wsp+4096,
             *w1dh = wsp+8192,     *w1dm = wsp+12288;           // stage1 64x64
    _Float16 *w2bh = wsp+16384,    *w2bm = wsp+24576,
             *w2dh = wsp+32768,    *w2dm = wsp+40960;           // stage2 64x128
    _Float16 *w3bh = wsp+49152,    *w3dh = wsp+81920;           // stage3 128x256

    float *f1s  = stats,       *f1q  = stats+512;
    float *f2s  = stats+1024,  *f2q  = stats+1280;
    float *cA0   = coefs,      *cB0   = coefs+64;
    float *cA1a  = coefs+128,  *cB1a  = coefs+192;
    float *cA1b  = coefs+256,  *cB1b  = coefs+320;
    float *cA2a  = coefs+384,  *cB2a  = coefs+512;
    float *cA2b  = coefs+640,  *cB2b  = coefs+768;
    float *cA3a  = coefs+896,  *cB3a  = coefs+1152;
    float *cA3b  = coefs+1408, *cB3b  = coefs+1664;

    (void)hipMemsetAsync(stats, 0, 2048*4, stream);

    // -------- weight prep (merged single launch) --------
    k_wprep_all<<<176, 256, 0, stream>>>(w1a, w2a, w3a,
                                         w1bh, w1bm, w1dh, w1dm,
                                         w2bh, w2bm, w2dh, w2dm,
                                         w3bh, w3dh);

    // -------- input MLP (h0 stays raw; ec1 decodes) --------
    k_input<<<NPTS/256, 256, 0, stream>>>(x, w_in, h0);
    k_colstats_part<<<64, 256, 0, stream>>>(h0, pS, pQ);
    k_bnfin_part<<<1, 64, 0, stream>>>(pS, pQ, g_in, b_in, cA0, cB0, 256, 1.0f/NPTS);

    // -------- edge conv 1 (64 -> 64/64); knn fused into ec1 --------
    k_ec1<64,64,0><<<BB, 256, 0, stream>>>(h0, cA0, cB0, nullptr,
                                           w1bh, w1bm, w1dh, w1dm, idx,
                                           P, Q, pS, pQ);
    k_bnfin_part<<<1, 64, 0, stream>>>(pS, pQ, g1a, b1a, cA1a, cB1a, 2048, 1.0f/NEDGE);
    k_mm2s<64,64,1><<<dim3(BB,1), 256, 0, stream>>>(P, Q, idx, cA1a, cB1a, w1b, g1b,
                                                    (unsigned*)h1, pS, pQ);
    k_bnfin_part<<<1, 64, 0, stream>>>(pS, pQ, g1b, b1b, cA1b, cB1b, 512, 1.0f/NEDGE);

    // -------- edge conv 2 (64 -> 128/128); h1 stays encoded --------
    k_ec1<64,128,1><<<BB, 256, 0, stream>>>(h1, cA1b, cB1b, g1b,
                                            w2bh, w2bm, w2dh, w2dm, idx,
                                            P, Q, pS, pQ);
    k_bnfin_part<<<1, 128, 0, stream>>>(pS, pQ, g2a, b2a, cA2a, cB2a, 1024, 1.0f/NEDGE);
    k_mm2s<128,128,2><<<dim3(BB,1), 256, 0, stream>>>(P, Q, idx, cA2a, cB2a, w2b, g2b,
                                                      (unsigned*)h2, pS, pQ);
    k_bnfin_part<<<1, 128, 0, stream>>>(pS, pQ, g2b, b2b, cA2b, cB2b, 512, 1.0f/NEDGE);

    // -------- edge conv 3 (128 -> 256/256); h2 stays encoded --------
    k_ec1h<128,256><<<BB, 256, 0, stream>>>((const unsigned*)h2, cA2b, cB2b, g2b,
                                            w3bh, w3dh, idx,
                                            (_Float16*)P, (_Float16*)Q, pS, pQ);
    k_bnfin_part<<<1, 256, 0, stream>>>(pS, pQ, g3a, b3a, cA3a, cB3a, 512, 1.0f/NEDGE);
    k_mm2xh<256,256,2><<<dim3(BB,2), 256, 0, stream>>>((_Float16*)P, (_Float16*)Q, idx,
                                                       cA3a, cB3a, w3b, g3b,
                                                       (unsigned*)h3, pS, pQ);
    k_bnfin_part<<<1, 256, 0, stream>>>(pS, pQ, g3b, b3b, cA3b, cB3b, 512, 1.0f/NEDGE);

    // -------- classifier (pool decodes all three encoded h's) --------
    k_pool<<<BB, 256, 0, stream>>>((const unsigned*)h1, (const unsigned*)h2,
                                   (const unsigned*)h3,
                                   cA1b, cB1b, g1b, cA2b, cB2b, g2b, cA3b, cB3b, g3b,
                                   pooled);
    k_fc1<<<dim3(512/FC1R, 2), 256, 0, stream>>>(pooled, wc1, z1, f1s, f1q);
    k_fc2<<<512, 256, 0, stream>>>(z1, f1s, f1q, gc1, bc1, wc2, z2, f2s, f2q);
    k_fc3<<<2, 256, 0, stream>>>(z2, f2s, f2q, gc2, bc2, wc3, bc3, (float*)d_out);

    (void)in_sizes; (void)n_in; (void)out_size; (void)ws_size;
}